// Round 5
// baseline (375.464 us; speedup 1.0000x reference)
//
#include <hip/hip_runtime.h>
#include <math.h>

#define NBOX 1024
#define ROI_N 7
#define CH 32
#define FEAT (ROI_N*ROI_N*CH)   // 1568
#define K1PAD 1600              // FEAT padded to multiple of 64
#define HD 2048
#define NMS_THR_F 0.01f
#define NMS_OUT 100
#define MTRI_WORDS 8704         // sum_{b=0..15} 64*(16-b)

typedef _Float16 f16;
typedef f16 f16x8 __attribute__((ext_vector_type(8)));
typedef float f32x4 __attribute__((ext_vector_type(4)));

__device__ __forceinline__ void split_f16(float v, f16& h, f16& l) {
  h = (f16)v;
  l = (f16)((v - (float)h) * 4096.0f);
}

// ---------------- ROI align (both maps) + fuse -> f16 hi/lo split ----------------
__global__ __launch_bounds__(256) void roi_fuse_kernel(
    const float* __restrict__ img, const float* __restrict__ bev,
    const float* __restrict__ img_boxes, const float* __restrict__ bev_boxes,
    const float* __restrict__ img_mask, const float* __restrict__ bev_mask,
    f16* __restrict__ xh, f16* __restrict__ xl)
{
  const int b = blockIdx.x;
  const float mi = img_mask[0], mb = bev_mask[0];
  const float denom = mi + mb;

  const float iy0 = img_boxes[b*4+0], ix0 = img_boxes[b*4+1];
  const float iy1 = img_boxes[b*4+2], ix1 = img_boxes[b*4+3];
  const float by0 = bev_boxes[b*4+0], bx0 = bev_boxes[b*4+1];
  const float by1 = bev_boxes[b*4+2], bx1 = bev_boxes[b*4+3];

  for (int idx = threadIdx.x; idx < K1PAD; idx += 256) {
    if (idx >= FEAT) {
      xh[(size_t)b*K1PAD + idx] = (f16)0.0f;
      xl[(size_t)b*K1PAD + idx] = (f16)0.0f;
      continue;
    }
    const int ti  = idx / (ROI_N*CH);
    const int rem = idx - ti*(ROI_N*CH);
    const int tj  = rem >> 5;
    const int c   = rem & 31;
    const float tt_i = (ti == ROI_N-1) ? 1.0f : ti * (1.0f/(ROI_N-1));
    const float tt_j = (tj == ROI_N-1) ? 1.0f : tj * (1.0f/(ROI_N-1));

    float vi, vb;
    {
      const int H = 360, W = 1200;
      const float ys = (iy0 + (iy1 - iy0) * tt_i) * (float)(H-1);
      const float xs = (ix0 + (ix1 - ix0) * tt_j) * (float)(W-1);
      int y0 = (int)floorf(ys); y0 = y0 < 0 ? 0 : (y0 > H-1 ? H-1 : y0);
      int x0 = (int)floorf(xs); x0 = x0 < 0 ? 0 : (x0 > W-1 ? W-1 : x0);
      const int y1 = (y0+1 > H-1) ? H-1 : y0+1;
      const int x1 = (x0+1 > W-1) ? W-1 : x0+1;
      const float wy = ys - (float)y0;
      const float wx = xs - (float)x0;
      const float f00 = img[(y0*W + x0)*CH + c];
      const float f01 = img[(y0*W + x1)*CH + c];
      const float f10 = img[(y1*W + x0)*CH + c];
      const float f11 = img[(y1*W + x1)*CH + c];
      vi = f00*(1.0f-wy)*(1.0f-wx) + f01*(1.0f-wy)*wx
         + f10*wy*(1.0f-wx)        + f11*wy*wx;
    }
    {
      const int H = 700, W = 800;
      const float ys = (by0 + (by1 - by0) * tt_i) * (float)(H-1);
      const float xs = (bx0 + (bx1 - bx0) * tt_j) * (float)(W-1);
      int y0 = (int)floorf(ys); y0 = y0 < 0 ? 0 : (y0 > H-1 ? H-1 : y0);
      int x0 = (int)floorf(xs); x0 = x0 < 0 ? 0 : (x0 > W-1 ? W-1 : x0);
      const int y1 = (y0+1 > H-1) ? H-1 : y0+1;
      const int x1 = (x0+1 > W-1) ? W-1 : x0+1;
      const float wy = ys - (float)y0;
      const float wx = xs - (float)x0;
      const float f00 = bev[(y0*W + x0)*CH + c];
      const float f01 = bev[(y0*W + x1)*CH + c];
      const float f10 = bev[(y1*W + x0)*CH + c];
      const float f11 = bev[(y1*W + x1)*CH + c];
      vb = f00*(1.0f-wy)*(1.0f-wx) + f01*(1.0f-wy)*wx
         + f10*wy*(1.0f-wx)        + f11*wy*wx;
    }
    f16 h, l;
    split_f16((mi*vi + mb*vb) / denom, h, l);
    xh[(size_t)b*K1PAD + idx] = h;
    xl[(size_t)b*K1PAD + idx] = l;
  }
}

// ------- transpose + f16 hi/lo split: W[K][N] -> Wt[N][Kpad], vectorized --------
// grid (N/32, Kpad/64), 256 threads
__global__ __launch_bounds__(256) void convt_w_kernel(
    const float* __restrict__ W, f16* __restrict__ Wt_hi, f16* __restrict__ Wt_lo,
    int K, int Kpad, int N)
{
  __shared__ float t[64][33];
  const int tid = threadIdx.x;
  const int n0 = blockIdx.x * 32, k0 = blockIdx.y * 64;
#pragma unroll
  for (int p = 0; p < 8; ++p) {
    const int idx = tid + p*256;       // 0..2047
    const int kk = idx >> 5, nn = idx & 31;
    const int k = k0 + kk;
    t[kk][nn] = (k < K) ? W[(size_t)k*N + n0 + nn] : 0.0f;
  }
  __syncthreads();
  const int nn = tid >> 3;             // 0..31
  const int kg = (tid & 7) * 8;        // 0,8,..,56
  f16x8 h8, l8;
#pragma unroll
  for (int q = 0; q < 8; ++q) {
    const float v = t[kg + q][nn];
    f16 h, l;
    split_f16(v, h, l);
    h8[q] = h; l8[q] = l;
  }
  *(f16x8*)&Wt_hi[(size_t)(n0+nn)*Kpad + k0 + kg] = h8;
  *(f16x8*)&Wt_lo[(size_t)(n0+nn)*Kpad + k0 + kg] = l8;
}

// ---------------- MFMA GEMM, pure-f16 hi/lo operands, 3 MFMA streams ----------------
// C[M,N] = relu(A @ B^T + bias).  A = (Ah+Al/4096)[M][K], B^T rows = (Bh+Bl/4096)[N][K].
// Tile 64(M) x 128(N), BK=32, 128 threads = 2 waves (each wave: 64x64 = 4x4 frags 16x16x32).
// SPLIT_OUT: 1 -> write f16 hi/lo pair (for next GEMM), 0 -> write f32.
#define LOADG(KK)                                                              \
  do {                                                                         \
    _Pragma("unroll")                                                          \
    for (int j_ = 0; j_ < 2; ++j_) {                                           \
      const int ch_ = tid + j_*128;                                            \
      const int r_ = ch_ >> 2, c_ = (ch_ & 3) * 8;                             \
      pa_h[j_] = *(const f16x8*)&Ah_g[(size_t)(m0 + r_)*K + (KK) + c_];        \
      pa_l[j_] = *(const f16x8*)&Al_g[(size_t)(m0 + r_)*K + (KK) + c_];        \
    }                                                                          \
    _Pragma("unroll")                                                          \
    for (int j_ = 0; j_ < 4; ++j_) {                                           \
      const int ch_ = tid + j_*128;                                            \
      const int r_ = ch_ >> 2, c_ = (ch_ & 3) * 8;                             \
      pb_h[j_] = *(const f16x8*)&Bh_g[(size_t)(n0 + r_)*K + (KK) + c_];        \
      pb_l[j_] = *(const f16x8*)&Bl_g[(size_t)(n0 + r_)*K + (KK) + c_];        \
    }                                                                          \
  } while (0)

template<int SPLIT_OUT>
__global__ __launch_bounds__(128) void gemm_mfma(
    const f16* __restrict__ Ah_g, const f16* __restrict__ Al_g,
    const f16* __restrict__ Bh_g, const f16* __restrict__ Bl_g,
    const float* __restrict__ bias,
    float* __restrict__ Cf, f16* __restrict__ Ch, f16* __restrict__ Cl,
    int M, int N, int K)
{
  __shared__ f16 Ah[64][40], Al[64][40], Bh[128][40], Bl[128][40];
  const int tid = threadIdx.x;
  const int m0 = blockIdx.y * 64, n0 = blockIdx.x * 128;
  const int wn = tid >> 6, lane = tid & 63;
  const int frow = lane & 15, fkg = lane >> 4;

  f32x4 acc1[4][4], acc2[4][4];
#pragma unroll
  for (int i = 0; i < 4; ++i)
#pragma unroll
    for (int j = 0; j < 4; ++j)
#pragma unroll
      for (int r = 0; r < 4; ++r) { acc1[i][j][r] = 0.0f; acc2[i][j][r] = 0.0f; }

  f16x8 pa_h[2], pa_l[2], pb_h[4], pb_l[4];
  LOADG(0);

  for (int k0 = 0; k0 < K; k0 += 32) {
    __syncthreads();
#pragma unroll
    for (int j = 0; j < 2; ++j) {
      const int ch = tid + j*128, r = ch >> 2, c = (ch & 3) * 8;
      *(f16x8*)&Ah[r][c] = pa_h[j];
      *(f16x8*)&Al[r][c] = pa_l[j];
    }
#pragma unroll
    for (int j = 0; j < 4; ++j) {
      const int ch = tid + j*128, r = ch >> 2, c = (ch & 3) * 8;
      *(f16x8*)&Bh[r][c] = pb_h[j];
      *(f16x8*)&Bl[r][c] = pb_l[j];
    }
    __syncthreads();
    if (k0 + 32 < K) { LOADG(k0 + 32); }

    f16x8 bh[4], bl[4];
#pragma unroll
    for (int j = 0; j < 4; ++j) {
      bh[j] = *(const f16x8*)&Bh[wn*64 + j*16 + frow][fkg*8];
      bl[j] = *(const f16x8*)&Bl[wn*64 + j*16 + frow][fkg*8];
    }
#pragma unroll
    for (int i = 0; i < 4; ++i) {
      const f16x8 ah = *(const f16x8*)&Ah[i*16 + frow][fkg*8];
      const f16x8 al = *(const f16x8*)&Al[i*16 + frow][fkg*8];
#pragma unroll
      for (int j = 0; j < 4; ++j) {
        acc1[i][j] = __builtin_amdgcn_mfma_f32_16x16x32_f16(ah, bh[j], acc1[i][j], 0, 0, 0);
        acc2[i][j] = __builtin_amdgcn_mfma_f32_16x16x32_f16(ah, bl[j], acc2[i][j], 0, 0, 0);
        acc2[i][j] = __builtin_amdgcn_mfma_f32_16x16x32_f16(al, bh[j], acc2[i][j], 0, 0, 0);
      }
    }
  }

  const float s = 1.0f / 4096.0f;
#pragma unroll
  for (int i = 0; i < 4; ++i)
#pragma unroll
    for (int j = 0; j < 4; ++j) {
      const int col = n0 + wn*64 + j*16 + frow;
      const float bv = bias[col];
#pragma unroll
      for (int r = 0; r < 4; ++r) {
        const int row = m0 + i*16 + fkg*4 + r;
        float v = acc1[i][j][r] + acc2[i][j][r] * s + bv;
        v = fmaxf(v, 0.0f);
        if (SPLIT_OUT) {
          f16 h, l;
          split_f16(v, h, l);
          Ch[(size_t)row*N + col] = h;
          Cl[(size_t)row*N + col] = l;
        } else {
          Cf[(size_t)row*N + col] = v;
        }
      }
    }
}

// ---------------- heads ----------------
__global__ __launch_bounds__(256) void heads_kernel(
    const float* __restrict__ h,
    const float* __restrict__ Wc, const float* __restrict__ bc,
    const float* __restrict__ Wo, const float* __restrict__ bo,
    const float* __restrict__ Wa, const float* __restrict__ ba,
    const float* __restrict__ bev_abs,
    float* __restrict__ obj_soft, float* __restrict__ boxes,
    float* __restrict__ orient, float* __restrict__ scores)
{
  const int r = blockIdx.x;
  const int tid = threadIdx.x;
  float acc[14];
#pragma unroll
  for (int j = 0; j < 14; ++j) acc[j] = 0.0f;
  for (int k = tid; k < HD; k += 256) {
    const float hv = h[(size_t)r*HD + k];
    acc[0]  += hv * Wc[k*2+0];
    acc[1]  += hv * Wc[k*2+1];
#pragma unroll
    for (int j = 0; j < 10; ++j) acc[2+j] += hv * Wo[k*10+j];
    acc[12] += hv * Wa[k*2+0];
    acc[13] += hv * Wa[k*2+1];
  }
  __shared__ float red[14][256];
#pragma unroll
  for (int j = 0; j < 14; ++j) red[j][tid] = acc[j];
  __syncthreads();
  for (int s = 128; s > 0; s >>= 1) {
    if (tid < s) {
#pragma unroll
      for (int j = 0; j < 14; ++j) red[j][tid] += red[j][tid + s];
    }
    __syncthreads();
  }
  if (tid == 0) {
    const float obj0 = red[0][0] + bc[0];
    const float obj1 = red[1][0] + bc[1];
    float off0 = red[2][0] + bo[0];
    float off1 = red[3][0] + bo[1];
    float off2 = red[4][0] + bo[2];
    float off3 = red[5][0] + bo[3];
    const float a0 = red[12][0] + ba[0];
    const float a1 = red[13][0] + ba[1];

    const float m  = fmaxf(obj0, obj1);
    const float e0 = expf(obj0 - m), e1 = expf(obj1 - m);
    const float se = e0 + e1;
    obj_soft[r*2+0] = e0 / se;
    obj_soft[r*2+1] = e1 / se;
    orient[r] = atan2f(a1, a0);

    const float pb0 = bev_abs[r*4+0] + 0.1f*off0;
    const float pb1 = bev_abs[r*4+1] + 0.1f*off1;
    const float pb2 = bev_abs[r*4+2] + 0.1f*off2;
    const float pb3 = bev_abs[r*4+3] + 0.1f*off3;
    boxes[r*4+0] = fminf(pb0, pb2);
    boxes[r*4+1] = fminf(pb1, pb3);
    boxes[r*4+2] = fmaxf(pb0, pb2);
    boxes[r*4+3] = fmaxf(pb1, pb3);
    scores[r] = obj1;
  }
}

// ---------------- NMS stage 1: stable descending argsort (rank counting) ----------------
__global__ __launch_bounds__(128) void sort_kernel(
    const float* __restrict__ scores, const float* __restrict__ boxes,
    int* __restrict__ order, float4* __restrict__ sboxes, float* __restrict__ sarea)
{
  const int i = blockIdx.x * 128 + threadIdx.x;
  const float my = scores[i];
  int pos = 0;
  for (int j = 0; j < NBOX; ++j) {
    const float sj = scores[j];
    pos += (sj > my) || (sj == my && j < i);
  }
  const float b0 = boxes[i*4+0], b1 = boxes[i*4+1];
  const float b2 = boxes[i*4+2], b3 = boxes[i*4+3];
  order[pos]  = i;
  sboxes[pos] = make_float4(b0, b1, b2, b3);
  sarea[pos]  = fmaxf(b2 - b0, 0.0f) * fmaxf(b3 - b1, 0.0f);
}

// ---------------- NMS stage 2: triangular suppression bitmask ----------------
__device__ __forceinline__ int tri_base(int i) {
  const int b = i >> 6;
  return 64*(16*b - (b*(b-1))/2) + (i & 63)*(16 - b);
}

__global__ __launch_bounds__(256) void maskbuild_kernel(
    const float4* __restrict__ sboxes, const float* __restrict__ sarea,
    unsigned long long* __restrict__ Mtri)
{
  __shared__ float4 sb[NBOX];
  __shared__ float  sa[NBOX];
  const int tid = threadIdx.x;
  for (int t = tid; t < NBOX; t += 256) { sb[t] = sboxes[t]; sa[t] = sarea[t]; }
  __syncthreads();
  const int wv = tid >> 6, lane = tid & 63;
  for (int r = 0; r < 4; ++r) {
    const int i = blockIdx.x * 16 + wv * 4 + r;
    const float4 bi = sb[i];
    const float  ai = sa[i];
    const int b = i >> 6;
    const int base = tri_base(i);
    for (int w = b; w < 16; ++w) {
      const int j = w * 64 + lane;
      const float4 bj = sb[j];
      const float lt0 = fmaxf(bi.x, bj.x), lt1 = fmaxf(bi.y, bj.y);
      const float rb0 = fminf(bi.z, bj.z), rb1 = fminf(bi.w, bj.w);
      const float wq = fmaxf(rb0 - lt0, 0.0f), hq = fmaxf(rb1 - lt1, 0.0f);
      const float inter = wq * hq;
      const float iou = inter / (ai + sa[j] - inter + 1e-8f);
      const unsigned long long bits = __ballot((j > i) && (iou > NMS_THR_F));
      if (lane == 0) Mtri[base + (w - b)] = bits;
    }
  }
}

// ---------------- NMS stage 3: barrier-free greedy scan + output gather ----------------
__global__ __launch_bounds__(1024) void scan_out_kernel(
    const unsigned long long* __restrict__ Mtri_g, const int* __restrict__ order,
    const float4* __restrict__ sboxes, const float* __restrict__ obj_soft,
    const float* __restrict__ orient, float* __restrict__ out)
{
  __shared__ unsigned long long M[MTRI_WORDS];
  __shared__ unsigned long long keepw[16];
  const int tid = threadIdx.x;
  for (int t = tid; t < MTRI_WORDS; t += 1024) M[t] = Mtri_g[t];
  __syncthreads();

  if (tid < 64) {
    const int lane = tid;
    unsigned long long kw = (lane < 16) ? ~0ull : 0ull;
    for (int w = 0; w < 16; ++w) {
      unsigned long long rem = __shfl(kw, w);
      while (rem) {
        const int bpos = __builtin_ctzll(rem);
        const int i = w * 64 + bpos;
        const int base = tri_base(i);
        unsigned long long m = 0;
        if (lane >= w && lane < 16) m = M[base + (lane - w)];
        kw &= ~m;
        const unsigned long long updated = __shfl(kw, w);
        rem = (bpos == 63) ? 0ull : (updated & (~0ull << (bpos + 1)));
      }
    }
    if (lane < 16) keepw[lane] = kw;
  }
  __syncthreads();

  const int w = tid >> 6, bpos = tid & 63;
  int pre = 0, total = 0;
#pragma unroll
  for (int q = 0; q < 16; ++q) {
    const int pc = __popcll(keepw[q]);
    total += pc;
    if (q < w) pre += pc;
  }
  pre += __popcll(keepw[w] & ((bpos == 0) ? 0ull : (~0ull >> (64 - bpos))));
  const int keep_self = (int)((keepw[w] >> bpos) & 1ull);
  const int rank = keep_self ? pre : (total + tid - pre);

  if (rank < NMS_OUT) {
    const int ob = order[tid];
    const float4 bx = sboxes[tid];
    out[rank*7+0] = obj_soft[ob*2+0];
    out[rank*7+1] = obj_soft[ob*2+1];
    out[rank*7+2] = bx.x;
    out[rank*7+3] = bx.y;
    out[rank*7+4] = bx.z;
    out[rank*7+5] = bx.w;
    out[rank*7+6] = orient[ob];
  }
}

extern "C" void kernel_launch(void* const* d_in, const int* in_sizes, int n_in,
                              void* d_out, int out_size, void* d_ws, size_t ws_size,
                              hipStream_t stream) {
  (void)in_sizes; (void)n_in; (void)out_size; (void)ws_size;
  const float* img       = (const float*)d_in[0];
  const float* bev       = (const float*)d_in[1];
  const float* img_boxes = (const float*)d_in[2];
  const float* bev_boxes = (const float*)d_in[3];
  const float* bev_abs   = (const float*)d_in[4];
  const float* img_mask  = (const float*)d_in[5];
  const float* bev_mask  = (const float*)d_in[6];
  const float* W1 = (const float*)d_in[7];
  const float* b1 = (const float*)d_in[8];
  const float* W2 = (const float*)d_in[9];
  const float* b2 = (const float*)d_in[10];
  const float* Wc = (const float*)d_in[11];
  const float* bc = (const float*)d_in[12];
  const float* Wo = (const float*)d_in[13];
  const float* bo = (const float*)d_in[14];
  const float* Wa = (const float*)d_in[15];
  const float* ba = (const float*)d_in[16];
  float* out = (float*)d_out;

  char* ws = (char*)d_ws;
  f16* xh    = (f16*)ws;                                  ws += (size_t)NBOX*K1PAD*2;
  f16* xl    = (f16*)ws;                                  ws += (size_t)NBOX*K1PAD*2;
  f16* h1h   = (f16*)ws;                                  ws += (size_t)NBOX*HD*2;
  f16* h1l   = (f16*)ws;                                  ws += (size_t)NBOX*HD*2;
  float* h2  = (float*)ws;                                ws += (size_t)NBOX*HD*4;
  f16* Wt1h  = (f16*)ws;                                  ws += (size_t)HD*K1PAD*2;
  f16* Wt1l  = (f16*)ws;                                  ws += (size_t)HD*K1PAD*2;
  f16* Wt2h  = (f16*)ws;                                  ws += (size_t)HD*HD*2;
  f16* Wt2l  = (f16*)ws;                                  ws += (size_t)HD*HD*2;
  float* obj_soft = (float*)ws;                           ws += NBOX*2*4;
  float* boxesf   = (float*)ws;                           ws += NBOX*4*4;
  float* orient   = (float*)ws;                           ws += NBOX*4;
  float* scores   = (float*)ws;                           ws += NBOX*4;
  int*   order    = (int*)ws;                             ws += NBOX*4;
  float4* sboxes  = (float4*)ws;                          ws += NBOX*16;
  float* sarea    = (float*)ws;                           ws += NBOX*4;
  unsigned long long* Mtri = (unsigned long long*)ws;

  roi_fuse_kernel<<<NBOX, 256, 0, stream>>>(img, bev, img_boxes, bev_boxes,
                                            img_mask, bev_mask, xh, xl);
  convt_w_kernel<<<dim3(HD/32, K1PAD/64), 256, 0, stream>>>(W1, Wt1h, Wt1l, FEAT, K1PAD, HD);
  convt_w_kernel<<<dim3(HD/32, HD/64),    256, 0, stream>>>(W2, Wt2h, Wt2l, HD, HD, HD);
  gemm_mfma<1><<<dim3(HD/128, NBOX/64), 128, 0, stream>>>(
      xh, xl, Wt1h, Wt1l, b1, (float*)nullptr, h1h, h1l, NBOX, HD, K1PAD);
  gemm_mfma<0><<<dim3(HD/128, NBOX/64), 128, 0, stream>>>(
      h1h, h1l, Wt2h, Wt2l, b2, h2, (f16*)nullptr, (f16*)nullptr, NBOX, HD, HD);
  heads_kernel<<<NBOX, 256, 0, stream>>>(h2, Wc, bc, Wo, bo, Wa, ba, bev_abs,
                                         obj_soft, boxesf, orient, scores);
  sort_kernel<<<8, 128, 0, stream>>>(scores, boxesf, order, sboxes, sarea);
  maskbuild_kernel<<<64, 256, 0, stream>>>(sboxes, sarea, Mtri);
  scan_out_kernel<<<1, 1024, 0, stream>>>(Mtri, order, sboxes, obj_soft, orient, out);
}

// Round 6
// 370.293 us; speedup vs baseline: 1.0140x; 1.0140x over previous
//
#include <hip/hip_runtime.h>
#include <math.h>

#define NBOX 1024
#define ROI_N 7
#define CH 32
#define FEAT (ROI_N*ROI_N*CH)   // 1568
#define K1PAD 1664              // FEAT padded to multiple of 128 (4 k-chunks x 32)
#define HD 2048
#define NMS_THR_F 0.01f
#define NMS_OUT 100
#define MTRI_WORDS 8704         // sum_{b=0..15} 64*(16-b)

typedef _Float16 f16;
typedef f16 f16x8 __attribute__((ext_vector_type(8)));
typedef float f32x4 __attribute__((ext_vector_type(4)));

__device__ __forceinline__ void split_f16(float v, f16& h, f16& l) {
  h = (f16)v;
  l = (f16)((v - (float)h) * 4096.0f);
}

// ---------------- ROI align (both maps) + fuse -> f16 hi/lo split ----------------
__global__ __launch_bounds__(256) void roi_fuse_kernel(
    const float* __restrict__ img, const float* __restrict__ bev,
    const float* __restrict__ img_boxes, const float* __restrict__ bev_boxes,
    const float* __restrict__ img_mask, const float* __restrict__ bev_mask,
    f16* __restrict__ xh, f16* __restrict__ xl)
{
  const int b = blockIdx.x;
  const float mi = img_mask[0], mb = bev_mask[0];
  const float denom = mi + mb;

  const float iy0 = img_boxes[b*4+0], ix0 = img_boxes[b*4+1];
  const float iy1 = img_boxes[b*4+2], ix1 = img_boxes[b*4+3];
  const float by0 = bev_boxes[b*4+0], bx0 = bev_boxes[b*4+1];
  const float by1 = bev_boxes[b*4+2], bx1 = bev_boxes[b*4+3];

  for (int idx = threadIdx.x; idx < K1PAD; idx += 256) {
    if (idx >= FEAT) {
      xh[(size_t)b*K1PAD + idx] = (f16)0.0f;
      xl[(size_t)b*K1PAD + idx] = (f16)0.0f;
      continue;
    }
    const int ti  = idx / (ROI_N*CH);
    const int rem = idx - ti*(ROI_N*CH);
    const int tj  = rem >> 5;
    const int c   = rem & 31;
    const float tt_i = (ti == ROI_N-1) ? 1.0f : ti * (1.0f/(ROI_N-1));
    const float tt_j = (tj == ROI_N-1) ? 1.0f : tj * (1.0f/(ROI_N-1));

    float vi, vb;
    {
      const int H = 360, W = 1200;
      const float ys = (iy0 + (iy1 - iy0) * tt_i) * (float)(H-1);
      const float xs = (ix0 + (ix1 - ix0) * tt_j) * (float)(W-1);
      int y0 = (int)floorf(ys); y0 = y0 < 0 ? 0 : (y0 > H-1 ? H-1 : y0);
      int x0 = (int)floorf(xs); x0 = x0 < 0 ? 0 : (x0 > W-1 ? W-1 : x0);
      const int y1 = (y0+1 > H-1) ? H-1 : y0+1;
      const int x1 = (x0+1 > W-1) ? W-1 : x0+1;
      const float wy = ys - (float)y0;
      const float wx = xs - (float)x0;
      const float f00 = img[(y0*W + x0)*CH + c];
      const float f01 = img[(y0*W + x1)*CH + c];
      const float f10 = img[(y1*W + x0)*CH + c];
      const float f11 = img[(y1*W + x1)*CH + c];
      vi = f00*(1.0f-wy)*(1.0f-wx) + f01*(1.0f-wy)*wx
         + f10*wy*(1.0f-wx)        + f11*wy*wx;
    }
    {
      const int H = 700, W = 800;
      const float ys = (by0 + (by1 - by0) * tt_i) * (float)(H-1);
      const float xs = (bx0 + (bx1 - bx0) * tt_j) * (float)(W-1);
      int y0 = (int)floorf(ys); y0 = y0 < 0 ? 0 : (y0 > H-1 ? H-1 : y0);
      int x0 = (int)floorf(xs); x0 = x0 < 0 ? 0 : (x0 > W-1 ? W-1 : x0);
      const int y1 = (y0+1 > H-1) ? H-1 : y0+1;
      const int x1 = (x0+1 > W-1) ? W-1 : x0+1;
      const float wy = ys - (float)y0;
      const float wx = xs - (float)x0;
      const float f00 = bev[(y0*W + x0)*CH + c];
      const float f01 = bev[(y0*W + x1)*CH + c];
      const float f10 = bev[(y1*W + x0)*CH + c];
      const float f11 = bev[(y1*W + x1)*CH + c];
      vb = f00*(1.0f-wy)*(1.0f-wx) + f01*(1.0f-wy)*wx
         + f10*wy*(1.0f-wx)        + f11*wy*wx;
    }
    f16 h, l;
    split_f16((mi*vi + mb*vb) / denom, h, l);
    xh[(size_t)b*K1PAD + idx] = h;
    xl[(size_t)b*K1PAD + idx] = l;
  }
}

// ------- transpose + f16 hi/lo split: W[K][N] -> Wt[N][Kpad], vectorized --------
__global__ __launch_bounds__(256) void convt_w_kernel(
    const float* __restrict__ W, f16* __restrict__ Wt_hi, f16* __restrict__ Wt_lo,
    int K, int Kpad, int N)
{
  __shared__ float t[64][33];
  const int tid = threadIdx.x;
  const int n0 = blockIdx.x * 32, k0 = blockIdx.y * 64;
#pragma unroll
  for (int p = 0; p < 8; ++p) {
    const int idx = tid + p*256;       // 0..2047
    const int kk = idx >> 5, nn = idx & 31;
    const int k = k0 + kk;
    t[kk][nn] = (k < K) ? W[(size_t)k*N + n0 + nn] : 0.0f;
  }
  __syncthreads();
  const int nn = tid >> 3;             // 0..31
  const int kg = (tid & 7) * 8;        // 0,8,..,56
  f16x8 h8, l8;
#pragma unroll
  for (int q = 0; q < 8; ++q) {
    const float v = t[kg + q][nn];
    f16 h, l;
    split_f16(v, h, l);
    h8[q] = h; l8[q] = l;
  }
  *(f16x8*)&Wt_hi[(size_t)(n0+nn)*Kpad + k0 + kg] = h8;
  *(f16x8*)&Wt_lo[(size_t)(n0+nn)*Kpad + k0 + kg] = l8;
}

// ---------------- bias pre-init: h1f rows = b1, h2f rows = b2 ----------------
__global__ __launch_bounds__(256) void init_bias_kernel(
    const float* __restrict__ b1, const float* __restrict__ b2,
    float4* __restrict__ h1f, float4* __restrict__ h2f)
{
  const int idx = blockIdx.x*256 + threadIdx.x;      // 0 .. NBOX*HD/4-1
  const int c4 = idx & (HD/4 - 1);
  h1f[idx] = *(const float4*)&b1[c4*4];
  h2f[idx] = *(const float4*)&b2[c4*4];
}

// ---------------- MFMA GEMM: split-K=4, atomic accumulate, f16 hi/lo x3 ----------------
// Cout (pre-initialized with bias) += A @ B^T.
// AF32=0: A given as pre-split f16 hi/lo.  AF32=1: A = relu(Af_g) split on the fly.
// Block 256 thr = 4 waves (2x2), block tile 128x128, wave tile 64x64, BK=32.
// Grid: 1D 512 blocks, XCD-aware decode (8 XCDs x 2 n-blocks x 8 m-blocks x 4 k-chunks).
#define STAGE_LOAD(KK)                                                          \
  do {                                                                          \
    _Pragma("unroll")                                                           \
    for (int q_ = 0; q_ < 2; ++q_) {                                            \
      const int ch_ = tid + q_*256;                                             \
      const int r_ = ch_ >> 2, c_ = (ch_ & 3) * 8;                              \
      if constexpr (AF32) {                                                     \
        paf[q_][0] = *(const float4*)&Af_g[(size_t)(m0 + r_)*K + (KK) + c_];    \
        paf[q_][1] = *(const float4*)&Af_g[(size_t)(m0 + r_)*K + (KK) + c_ + 4];\
      } else {                                                                  \
        pah[q_] = *(const f16x8*)&Ah_g[(size_t)(m0 + r_)*K + (KK) + c_];        \
        pal[q_] = *(const f16x8*)&Al_g[(size_t)(m0 + r_)*K + (KK) + c_];        \
      }                                                                         \
      pbh[q_] = *(const f16x8*)&Bh_g[(size_t)(n0 + r_)*K + (KK) + c_];          \
      pbl[q_] = *(const f16x8*)&Bl_g[(size_t)(n0 + r_)*K + (KK) + c_];          \
    }                                                                           \
  } while (0)

template<int AF32>
__global__ __launch_bounds__(256, 2) void gemm_sk(
    const f16* __restrict__ Ah_g, const f16* __restrict__ Al_g,
    const float* __restrict__ Af_g,
    const f16* __restrict__ Bh_g, const f16* __restrict__ Bl_g,
    float* __restrict__ Cout, int M, int N, int K, int kchunk)
{
  __shared__ f16 Ah[128][32], Al[128][32], Bh[128][32], Bl[128][32];
  const int tid = threadIdx.x;

  const int g = blockIdx.x;
  const int xcd = g & 7, c = g >> 3;
  const int nb = xcd*2 + (c & 1);
  const int mb = (c >> 1) & 7;
  const int zb = c >> 4;
  const int m0 = mb * 128, n0 = nb * 128;
  const int kb = zb * kchunk, ke = kb + kchunk;

  const int wid = tid >> 6, lane = tid & 63;
  const int wr = wid >> 1, wc = wid & 1;
  const int frow = lane & 15, fkg = lane >> 4;
  const int swz = (fkg ^ ((frow >> 1) & 3)) * 8;   // f16 col offset for frag reads

  f32x4 acc1[4][4], acc2[4][4];
#pragma unroll
  for (int i = 0; i < 4; ++i)
#pragma unroll
    for (int j = 0; j < 4; ++j)
#pragma unroll
      for (int r = 0; r < 4; ++r) { acc1[i][j][r] = 0.0f; acc2[i][j][r] = 0.0f; }

  f16x8 pah[2], pal[2], pbh[2], pbl[2];
  float4 paf[2][2];

  STAGE_LOAD(kb);
  for (int kk = kb; kk < ke; kk += 32) {
    __syncthreads();
#pragma unroll
    for (int q = 0; q < 2; ++q) {
      const int ch = tid + q*256;
      const int r = ch >> 2, cs = ch & 3;
      const int sl = (cs ^ ((r >> 1) & 3)) * 8;
      if constexpr (AF32) {
        const float4 a0 = paf[q][0], a1 = paf[q][1];
        f16x8 hv, lv;
        { float v = fmaxf(a0.x, 0.0f); f16 h,l; split_f16(v,h,l); hv[0]=h; lv[0]=l; }
        { float v = fmaxf(a0.y, 0.0f); f16 h,l; split_f16(v,h,l); hv[1]=h; lv[1]=l; }
        { float v = fmaxf(a0.z, 0.0f); f16 h,l; split_f16(v,h,l); hv[2]=h; lv[2]=l; }
        { float v = fmaxf(a0.w, 0.0f); f16 h,l; split_f16(v,h,l); hv[3]=h; lv[3]=l; }
        { float v = fmaxf(a1.x, 0.0f); f16 h,l; split_f16(v,h,l); hv[4]=h; lv[4]=l; }
        { float v = fmaxf(a1.y, 0.0f); f16 h,l; split_f16(v,h,l); hv[5]=h; lv[5]=l; }
        { float v = fmaxf(a1.z, 0.0f); f16 h,l; split_f16(v,h,l); hv[6]=h; lv[6]=l; }
        { float v = fmaxf(a1.w, 0.0f); f16 h,l; split_f16(v,h,l); hv[7]=h; lv[7]=l; }
        *(f16x8*)&Ah[r][sl] = hv;
        *(f16x8*)&Al[r][sl] = lv;
      } else {
        *(f16x8*)&Ah[r][sl] = pah[q];
        *(f16x8*)&Al[r][sl] = pal[q];
      }
      *(f16x8*)&Bh[r][sl] = pbh[q];
      *(f16x8*)&Bl[r][sl] = pbl[q];
    }
    __syncthreads();
    if (kk + 32 < ke) { STAGE_LOAD(kk + 32); }

    f16x8 bh[4], bl[4];
#pragma unroll
    for (int j = 0; j < 4; ++j) {
      const int rr = wc*64 + j*16 + frow;
      bh[j] = *(const f16x8*)&Bh[rr][swz];
      bl[j] = *(const f16x8*)&Bl[rr][swz];
    }
#pragma unroll
    for (int i = 0; i < 4; ++i) {
      const int rr = wr*64 + i*16 + frow;
      const f16x8 ah = *(const f16x8*)&Ah[rr][swz];
      const f16x8 al = *(const f16x8*)&Al[rr][swz];
#pragma unroll
      for (int j = 0; j < 4; ++j) {
        acc1[i][j] = __builtin_amdgcn_mfma_f32_16x16x32_f16(ah, bh[j], acc1[i][j], 0, 0, 0);
        acc2[i][j] = __builtin_amdgcn_mfma_f32_16x16x32_f16(ah, bl[j], acc2[i][j], 0, 0, 0);
        acc2[i][j] = __builtin_amdgcn_mfma_f32_16x16x32_f16(al, bh[j], acc2[i][j], 0, 0, 0);
      }
    }
  }

  const float s = 1.0f / 4096.0f;
#pragma unroll
  for (int i = 0; i < 4; ++i)
#pragma unroll
    for (int j = 0; j < 4; ++j) {
      const int col = n0 + wc*64 + j*16 + frow;
#pragma unroll
      for (int r = 0; r < 4; ++r) {
        const int row = m0 + wr*64 + i*16 + fkg*4 + r;
        atomicAdd(&Cout[(size_t)row*N + col], acc1[i][j][r] + acc2[i][j][r] * s);
      }
    }
}

// ---------------- heads (applies relu(h2f)) ----------------
__global__ __launch_bounds__(256) void heads_kernel(
    const float* __restrict__ h2f,
    const float* __restrict__ Wc, const float* __restrict__ bc,
    const float* __restrict__ Wo, const float* __restrict__ bo,
    const float* __restrict__ Wa, const float* __restrict__ ba,
    const float* __restrict__ bev_abs,
    float* __restrict__ obj_soft, float* __restrict__ boxes,
    float* __restrict__ orient, float* __restrict__ scores)
{
  const int r = blockIdx.x;
  const int tid = threadIdx.x;
  float acc[14];
#pragma unroll
  for (int j = 0; j < 14; ++j) acc[j] = 0.0f;
  for (int k = tid; k < HD; k += 256) {
    const float hv = fmaxf(h2f[(size_t)r*HD + k], 0.0f);
    acc[0]  += hv * Wc[k*2+0];
    acc[1]  += hv * Wc[k*2+1];
#pragma unroll
    for (int j = 0; j < 10; ++j) acc[2+j] += hv * Wo[k*10+j];
    acc[12] += hv * Wa[k*2+0];
    acc[13] += hv * Wa[k*2+1];
  }
  __shared__ float red[14][256];
#pragma unroll
  for (int j = 0; j < 14; ++j) red[j][tid] = acc[j];
  __syncthreads();
  for (int s = 128; s > 0; s >>= 1) {
    if (tid < s) {
#pragma unroll
      for (int j = 0; j < 14; ++j) red[j][tid] += red[j][tid + s];
    }
    __syncthreads();
  }
  if (tid == 0) {
    const float obj0 = red[0][0] + bc[0];
    const float obj1 = red[1][0] + bc[1];
    float off0 = red[2][0] + bo[0];
    float off1 = red[3][0] + bo[1];
    float off2 = red[4][0] + bo[2];
    float off3 = red[5][0] + bo[3];
    const float a0 = red[12][0] + ba[0];
    const float a1 = red[13][0] + ba[1];

    const float m  = fmaxf(obj0, obj1);
    const float e0 = expf(obj0 - m), e1 = expf(obj1 - m);
    const float se = e0 + e1;
    obj_soft[r*2+0] = e0 / se;
    obj_soft[r*2+1] = e1 / se;
    orient[r] = atan2f(a1, a0);

    const float pb0 = bev_abs[r*4+0] + 0.1f*off0;
    const float pb1 = bev_abs[r*4+1] + 0.1f*off1;
    const float pb2 = bev_abs[r*4+2] + 0.1f*off2;
    const float pb3 = bev_abs[r*4+3] + 0.1f*off3;
    boxes[r*4+0] = fminf(pb0, pb2);
    boxes[r*4+1] = fminf(pb1, pb3);
    boxes[r*4+2] = fmaxf(pb0, pb2);
    boxes[r*4+3] = fmaxf(pb1, pb3);
    scores[r] = obj1;
  }
}

// ---------------- NMS stage 1: stable descending argsort (rank counting) ----------------
__global__ __launch_bounds__(128) void sort_kernel(
    const float* __restrict__ scores, const float* __restrict__ boxes,
    int* __restrict__ order, float4* __restrict__ sboxes, float* __restrict__ sarea)
{
  const int i = blockIdx.x * 128 + threadIdx.x;
  const float my = scores[i];
  int pos = 0;
  for (int j = 0; j < NBOX; ++j) {
    const float sj = scores[j];
    pos += (sj > my) || (sj == my && j < i);
  }
  const float b0 = boxes[i*4+0], b1 = boxes[i*4+1];
  const float b2 = boxes[i*4+2], b3 = boxes[i*4+3];
  order[pos]  = i;
  sboxes[pos] = make_float4(b0, b1, b2, b3);
  sarea[pos]  = fmaxf(b2 - b0, 0.0f) * fmaxf(b3 - b1, 0.0f);
}

// ---------------- NMS stage 2: triangular suppression bitmask ----------------
__device__ __forceinline__ int tri_base(int i) {
  const int b = i >> 6;
  return 64*(16*b - (b*(b-1))/2) + (i & 63)*(16 - b);
}

__global__ __launch_bounds__(256) void maskbuild_kernel(
    const float4* __restrict__ sboxes, const float* __restrict__ sarea,
    unsigned long long* __restrict__ Mtri)
{
  __shared__ float4 sb[NBOX];
  __shared__ float  sa[NBOX];
  const int tid = threadIdx.x;
  for (int t = tid; t < NBOX; t += 256) { sb[t] = sboxes[t]; sa[t] = sarea[t]; }
  __syncthreads();
  const int wv = tid >> 6, lane = tid & 63;
  for (int r = 0; r < 4; ++r) {
    const int i = blockIdx.x * 16 + wv * 4 + r;
    const float4 bi = sb[i];
    const float  ai = sa[i];
    const int b = i >> 6;
    const int base = tri_base(i);
    for (int w = b; w < 16; ++w) {
      const int j = w * 64 + lane;
      const float4 bj = sb[j];
      const float lt0 = fmaxf(bi.x, bj.x), lt1 = fmaxf(bi.y, bj.y);
      const float rb0 = fminf(bi.z, bj.z), rb1 = fminf(bi.w, bj.w);
      const float wq = fmaxf(rb0 - lt0, 0.0f), hq = fmaxf(rb1 - lt1, 0.0f);
      const float inter = wq * hq;
      const float iou = inter / (ai + sa[j] - inter + 1e-8f);
      const unsigned long long bits = __ballot((j > i) && (iou > NMS_THR_F));
      if (lane == 0) Mtri[base + (w - b)] = bits;
    }
  }
}

// ---------------- NMS stage 3: barrier-free greedy scan + output gather ----------------
__global__ __launch_bounds__(1024) void scan_out_kernel(
    const unsigned long long* __restrict__ Mtri_g, const int* __restrict__ order,
    const float4* __restrict__ sboxes, const float* __restrict__ obj_soft,
    const float* __restrict__ orient, float* __restrict__ out)
{
  __shared__ unsigned long long M[MTRI_WORDS];
  __shared__ unsigned long long keepw[16];
  const int tid = threadIdx.x;
  for (int t = tid; t < MTRI_WORDS; t += 1024) M[t] = Mtri_g[t];
  __syncthreads();

  if (tid < 64) {
    const int lane = tid;
    unsigned long long kw = (lane < 16) ? ~0ull : 0ull;
    for (int w = 0; w < 16; ++w) {
      unsigned long long rem = __shfl(kw, w);
      while (rem) {
        const int bpos = __builtin_ctzll(rem);
        const int i = w * 64 + bpos;
        const int base = tri_base(i);
        unsigned long long m = 0;
        if (lane >= w && lane < 16) m = M[base + (lane - w)];
        kw &= ~m;
        const unsigned long long updated = __shfl(kw, w);
        rem = (bpos == 63) ? 0ull : (updated & (~0ull << (bpos + 1)));
      }
    }
    if (lane < 16) keepw[lane] = kw;
  }
  __syncthreads();

  const int w = tid >> 6, bpos = tid & 63;
  int pre = 0, total = 0;
#pragma unroll
  for (int q = 0; q < 16; ++q) {
    const int pc = __popcll(keepw[q]);
    total += pc;
    if (q < w) pre += pc;
  }
  pre += __popcll(keepw[w] & ((bpos == 0) ? 0ull : (~0ull >> (64 - bpos))));
  const int keep_self = (int)((keepw[w] >> bpos) & 1ull);
  const int rank = keep_self ? pre : (total + tid - pre);

  if (rank < NMS_OUT) {
    const int ob = order[tid];
    const float4 bx = sboxes[tid];
    out[rank*7+0] = obj_soft[ob*2+0];
    out[rank*7+1] = obj_soft[ob*2+1];
    out[rank*7+2] = bx.x;
    out[rank*7+3] = bx.y;
    out[rank*7+4] = bx.z;
    out[rank*7+5] = bx.w;
    out[rank*7+6] = orient[ob];
  }
}

extern "C" void kernel_launch(void* const* d_in, const int* in_sizes, int n_in,
                              void* d_out, int out_size, void* d_ws, size_t ws_size,
                              hipStream_t stream) {
  (void)in_sizes; (void)n_in; (void)out_size; (void)ws_size;
  const float* img       = (const float*)d_in[0];
  const float* bev       = (const float*)d_in[1];
  const float* img_boxes = (const float*)d_in[2];
  const float* bev_boxes = (const float*)d_in[3];
  const float* bev_abs   = (const float*)d_in[4];
  const float* img_mask  = (const float*)d_in[5];
  const float* bev_mask  = (const float*)d_in[6];
  const float* W1 = (const float*)d_in[7];
  const float* b1 = (const float*)d_in[8];
  const float* W2 = (const float*)d_in[9];
  const float* b2 = (const float*)d_in[10];
  const float* Wc = (const float*)d_in[11];
  const float* bc = (const float*)d_in[12];
  const float* Wo = (const float*)d_in[13];
  const float* bo = (const float*)d_in[14];
  const float* Wa = (const float*)d_in[15];
  const float* ba = (const float*)d_in[16];
  float* out = (float*)d_out;

  char* ws = (char*)d_ws;
  f16* xh    = (f16*)ws;                                  ws += (size_t)NBOX*K1PAD*2;
  f16* xl    = (f16*)ws;                                  ws += (size_t)NBOX*K1PAD*2;
  float* h1f = (float*)ws;                                ws += (size_t)NBOX*HD*4;
  float* h2f = (float*)ws;                                ws += (size_t)NBOX*HD*4;
  f16* Wt1h  = (f16*)ws;                                  ws += (size_t)HD*K1PAD*2;
  f16* Wt1l  = (f16*)ws;                                  ws += (size_t)HD*K1PAD*2;
  f16* Wt2h  = (f16*)ws;                                  ws += (size_t)HD*HD*2;
  f16* Wt2l  = (f16*)ws;                                  ws += (size_t)HD*HD*2;
  float* obj_soft = (float*)ws;                           ws += NBOX*2*4;
  float* boxesf   = (float*)ws;                           ws += NBOX*4*4;
  float* orient   = (float*)ws;                           ws += NBOX*4;
  float* scores   = (float*)ws;                           ws += NBOX*4;
  int*   order    = (int*)ws;                             ws += NBOX*4;
  float4* sboxes  = (float4*)ws;                          ws += NBOX*16;
  float* sarea    = (float*)ws;                           ws += NBOX*4;
  unsigned long long* Mtri = (unsigned long long*)ws;

  roi_fuse_kernel<<<NBOX, 256, 0, stream>>>(img, bev, img_boxes, bev_boxes,
                                            img_mask, bev_mask, xh, xl);
  init_bias_kernel<<<NBOX*HD/4/256, 256, 0, stream>>>(b1, b2, (float4*)h1f, (float4*)h2f);
  convt_w_kernel<<<dim3(HD/32, K1PAD/64), 256, 0, stream>>>(W1, Wt1h, Wt1l, FEAT, K1PAD, HD);
  convt_w_kernel<<<dim3(HD/32, HD/64),    256, 0, stream>>>(W2, Wt2h, Wt2l, HD, HD, HD);
  // gemm1: h1f = b1 + x @ W1  (pre-split f16 A)
  gemm_sk<0><<<512, 256, 0, stream>>>(xh, xl, (const float*)nullptr,
                                      Wt1h, Wt1l, h1f, NBOX, HD, K1PAD, K1PAD/4);
  // gemm2: h2f = b2 + relu(h1f) @ W2  (f32 A, relu+split in staging)
  gemm_sk<1><<<512, 256, 0, stream>>>((const f16*)nullptr, (const f16*)nullptr, h1f,
                                      Wt2h, Wt2l, h2f, NBOX, HD, HD, HD/4);
  heads_kernel<<<NBOX, 256, 0, stream>>>(h2f, Wc, bc, Wo, bo, Wa, ba, bev_abs,
                                         obj_soft, boxesf, orient, scores);
  sort_kernel<<<8, 128, 0, stream>>>(scores, boxesf, order, sboxes, sarea);
  maskbuild_kernel<<<64, 256, 0, stream>>>(sboxes, sarea, Mtri);
  scan_out_kernel<<<1, 1024, 0, stream>>>(Mtri, order, sboxes, obj_soft, orient, out);
}

// Round 7
// 359.170 us; speedup vs baseline: 1.0454x; 1.0310x over previous
//
#include <hip/hip_runtime.h>
#include <math.h>

#define NBOX 1024
#define ROI_N 7
#define CH 32
#define FEAT (ROI_N*ROI_N*CH)   // 1568
#define K1PAD 1664              // FEAT padded to multiple of 128
#define HD 2048
#define NMS_THR_F 0.01f
#define NMS_OUT 100
#define MTRI_WORDS 8704

typedef _Float16 f16;
typedef f16 f16x4 __attribute__((ext_vector_type(4)));
typedef f16 f16x8 __attribute__((ext_vector_type(8)));
typedef float f32x4 __attribute__((ext_vector_type(4)));

__device__ __forceinline__ void split_f16(float v, f16& h, f16& l) {
  h = (f16)v;
  l = (f16)((v - (float)h) * 4096.0f);
}

__device__ __forceinline__ void gload_lds16(const void* g, void* l) {
  __builtin_amdgcn_global_load_lds(
      (const __attribute__((address_space(1))) unsigned int*)g,
      (__attribute__((address_space(3))) unsigned int*)l, 16, 0, 0);
}

// ============ prep: roi_fuse + convt(W1) + convt(W2) + bias-init, range-dispatched ============
#define B_ROI 1024
#define B_C1  (64*26)    // (HD/32) x (K1PAD/64)
#define B_C2  (64*32)    // (HD/32) x (HD/64)
#define B_INIT 2048      // NBOX*HD/4/256

__device__ void roi_part(int b, int tid,
    const float* __restrict__ img, const float* __restrict__ bev,
    const float* __restrict__ img_boxes, const float* __restrict__ bev_boxes,
    float mi, float mb, f16* __restrict__ xh, f16* __restrict__ xl)
{
  const float denom = mi + mb;
  if (tid >= 196) {
    const int g = tid - 196;
    if (g < 12) {
      f16x8 z = {};
      *(f16x8*)&xh[(size_t)b*K1PAD + FEAT + g*8] = z;
      *(f16x8*)&xl[(size_t)b*K1PAD + FEAT + g*8] = z;
    }
    return;
  }
  const int cell = tid >> 2, cg = (tid & 3) * 8;
  const int ti = cell / ROI_N, tj = cell - ti*ROI_N;
  const float tt_i = (ti == 6) ? 1.0f : ti * (1.0f/6.0f);
  const float tt_j = (tj == 6) ? 1.0f : tj * (1.0f/6.0f);

  float vi[8], vb[8];
  {
    const int H = 360, W = 1200;
    const float iy0 = img_boxes[b*4+0], ix0 = img_boxes[b*4+1];
    const float iy1 = img_boxes[b*4+2], ix1 = img_boxes[b*4+3];
    const float ys = (iy0 + (iy1 - iy0) * tt_i) * (float)(H-1);
    const float xs = (ix0 + (ix1 - ix0) * tt_j) * (float)(W-1);
    int y0 = (int)floorf(ys); y0 = y0 < 0 ? 0 : (y0 > H-1 ? H-1 : y0);
    int x0 = (int)floorf(xs); x0 = x0 < 0 ? 0 : (x0 > W-1 ? W-1 : x0);
    const int y1 = (y0+1 > H-1) ? H-1 : y0+1;
    const int x1 = (x0+1 > W-1) ? W-1 : x0+1;
    const float wy = ys - (float)y0, wx = xs - (float)x0;
    const float w00 = (1.0f-wy)*(1.0f-wx), w01 = (1.0f-wy)*wx;
    const float w10 = wy*(1.0f-wx),        w11 = wy*wx;
    const float* p00 = &img[(y0*W + x0)*CH + cg];
    const float* p01 = &img[(y0*W + x1)*CH + cg];
    const float* p10 = &img[(y1*W + x0)*CH + cg];
    const float* p11 = &img[(y1*W + x1)*CH + cg];
#pragma unroll
    for (int q = 0; q < 2; ++q) {
      const float4 f00 = *(const float4*)(p00 + q*4);
      const float4 f01 = *(const float4*)(p01 + q*4);
      const float4 f10 = *(const float4*)(p10 + q*4);
      const float4 f11 = *(const float4*)(p11 + q*4);
      vi[q*4+0] = f00.x*w00 + f01.x*w01 + f10.x*w10 + f11.x*w11;
      vi[q*4+1] = f00.y*w00 + f01.y*w01 + f10.y*w10 + f11.y*w11;
      vi[q*4+2] = f00.z*w00 + f01.z*w01 + f10.z*w10 + f11.z*w11;
      vi[q*4+3] = f00.w*w00 + f01.w*w01 + f10.w*w10 + f11.w*w11;
    }
  }
  {
    const int H = 700, W = 800;
    const float by0 = bev_boxes[b*4+0], bx0 = bev_boxes[b*4+1];
    const float by1 = bev_boxes[b*4+2], bx1 = bev_boxes[b*4+3];
    const float ys = (by0 + (by1 - by0) * tt_i) * (float)(H-1);
    const float xs = (bx0 + (bx1 - bx0) * tt_j) * (float)(W-1);
    int y0 = (int)floorf(ys); y0 = y0 < 0 ? 0 : (y0 > H-1 ? H-1 : y0);
    int x0 = (int)floorf(xs); x0 = x0 < 0 ? 0 : (x0 > W-1 ? W-1 : x0);
    const int y1 = (y0+1 > H-1) ? H-1 : y0+1;
    const int x1 = (x0+1 > W-1) ? W-1 : x0+1;
    const float wy = ys - (float)y0, wx = xs - (float)x0;
    const float w00 = (1.0f-wy)*(1.0f-wx), w01 = (1.0f-wy)*wx;
    const float w10 = wy*(1.0f-wx),        w11 = wy*wx;
    const float* p00 = &bev[(y0*W + x0)*CH + cg];
    const float* p01 = &bev[(y0*W + x1)*CH + cg];
    const float* p10 = &bev[(y1*W + x0)*CH + cg];
    const float* p11 = &bev[(y1*W + x1)*CH + cg];
#pragma unroll
    for (int q = 0; q < 2; ++q) {
      const float4 f00 = *(const float4*)(p00 + q*4);
      const float4 f01 = *(const float4*)(p01 + q*4);
      const float4 f10 = *(const float4*)(p10 + q*4);
      const float4 f11 = *(const float4*)(p11 + q*4);
      vb[q*4+0] = f00.x*w00 + f01.x*w01 + f10.x*w10 + f11.x*w11;
      vb[q*4+1] = f00.y*w00 + f01.y*w01 + f10.y*w10 + f11.y*w11;
      vb[q*4+2] = f00.z*w00 + f01.z*w01 + f10.z*w10 + f11.z*w11;
      vb[q*4+3] = f00.w*w00 + f01.w*w01 + f10.w*w10 + f11.w*w11;
    }
  }
  f16x8 h8, l8;
#pragma unroll
  for (int q = 0; q < 8; ++q) {
    f16 h, l;
    split_f16((mi*vi[q] + mb*vb[q]) / denom, h, l);
    h8[q] = h; l8[q] = l;
  }
  const size_t o = (size_t)b*K1PAD + cell*32 + cg;
  *(f16x8*)&xh[o] = h8;
  *(f16x8*)&xl[o] = l8;
}

__global__ __launch_bounds__(256) void prep_kernel(
    const float* __restrict__ img, const float* __restrict__ bev,
    const float* __restrict__ img_boxes, const float* __restrict__ bev_boxes,
    const float* __restrict__ img_mask, const float* __restrict__ bev_mask,
    f16* __restrict__ xh, f16* __restrict__ xl,
    const float* __restrict__ W1, f16* __restrict__ Wt1h, f16* __restrict__ Wt1l,
    const float* __restrict__ W2, f16* __restrict__ Wt2h, f16* __restrict__ Wt2l,
    const float* __restrict__ b1, const float* __restrict__ b2,
    float4* __restrict__ h1f, float4* __restrict__ h2f)
{
  __shared__ float t[64][33];
  const int g = blockIdx.x;
  const int tid = threadIdx.x;

  if (g < B_ROI) {
    roi_part(g, tid, img, bev, img_boxes, bev_boxes, img_mask[0], bev_mask[0], xh, xl);
    return;
  }
  const float* W; f16 *Wh, *Wl; int K, Kpad, cb;
  if (g < B_ROI + B_C1) { cb = g - B_ROI;        W = W1; Wh = Wt1h; Wl = Wt1l; K = FEAT; Kpad = K1PAD; }
  else if (g < B_ROI + B_C1 + B_C2) { cb = g - B_ROI - B_C1; W = W2; Wh = Wt2h; Wl = Wt2l; K = HD; Kpad = HD; }
  else {
    const int ib = g - B_ROI - B_C1 - B_C2;
    const int idx = ib*256 + tid;
    const int c4 = idx & (HD/4 - 1);
    h1f[idx] = *(const float4*)&b1[c4*4];
    h2f[idx] = *(const float4*)&b2[c4*4];
    return;
  }
  // transpose + split: W[K][HD] -> Wt[HD][Kpad]
  const int nt = cb & 63, kt = cb >> 6;
  const int n0 = nt * 32, k0 = kt * 64;
#pragma unroll
  for (int p = 0; p < 8; ++p) {
    const int idx = tid + p*256;
    const int kk = idx >> 5, nn = idx & 31;
    const int k = k0 + kk;
    t[kk][nn] = (k < K) ? W[(size_t)k*HD + n0 + nn] : 0.0f;
  }
  __syncthreads();
  const int nn = tid >> 3;
  const int kg = (tid & 7) * 8;
  f16x8 h8, l8;
#pragma unroll
  for (int q = 0; q < 8; ++q) {
    f16 h, l;
    split_f16(t[kg + q][nn], h, l);
    h8[q] = h; l8[q] = l;
  }
  *(f16x8*)&Wh[(size_t)(n0+nn)*Kpad + k0 + kg] = h8;
  *(f16x8*)&Wl[(size_t)(n0+nn)*Kpad + k0 + kg] = l8;
}

// ---------------- relu + f16 hi/lo split of h1 ----------------
__global__ __launch_bounds__(256) void split_relu_kernel(
    const float* __restrict__ in, f16* __restrict__ oh, f16* __restrict__ ol)
{
  const int idx = blockIdx.x*256 + threadIdx.x;   // one float4 each
  const float4 v = *(const float4*)&in[idx*4];
  f16x4 h4, l4;
  { f16 h,l; split_f16(fmaxf(v.x,0.0f),h,l); h4[0]=h; l4[0]=l; }
  { f16 h,l; split_f16(fmaxf(v.y,0.0f),h,l); h4[1]=h; l4[1]=l; }
  { f16 h,l; split_f16(fmaxf(v.z,0.0f),h,l); h4[2]=h; l4[2]=l; }
  { f16 h,l; split_f16(fmaxf(v.w,0.0f),h,l); h4[3]=h; l4[3]=l; }
  *(f16x4*)&oh[idx*4] = h4;
  *(f16x4*)&ol[idx*4] = l4;
}

// ---------------- MFMA GEMM: split-K=4 atomics, pure-f16 hi/lo, global_load_lds ----------------
// Cout (pre-initialized with bias) += (Ah+Al/4096) @ (Bh+Bl/4096)^T, dropping lo*lo.
// Block 256 thr = 4 waves (2x2), tile 128x128, BK=32. Grid 512, XCD-aware decode.
// LDS linear dest via global_load_lds; source column pre-swizzled (XOR), read swizzled.
__global__ __launch_bounds__(256, 2) void gemm_sk(
    const f16* __restrict__ Ah_g, const f16* __restrict__ Al_g,
    const f16* __restrict__ Bh_g, const f16* __restrict__ Bl_g,
    float* __restrict__ Cout, int M, int N, int K, int kchunk)
{
  __shared__ __align__(16) f16 Ah[128][32], Al[128][32], Bh[128][32], Bl[128][32];
  const int tid = threadIdx.x;

  const int g = blockIdx.x;
  const int xcd = g & 7, c = g >> 3;
  const int nb = xcd*2 + (c & 1);
  const int mb = (c >> 1) & 7;
  const int zb = c >> 4;
  const int m0 = mb * 128, n0 = nb * 128;
  const int kb = zb * kchunk, ke = kb + kchunk;

  const int wid = tid >> 6, lane = tid & 63;
  const int wr = wid >> 1, wc = wid & 1;
  const int frow = lane & 15, fkg = lane >> 4;
  const int swz = (fkg ^ ((frow >> 1) & 3)) * 8;

  // per-wave staging assignment: wave -> one LDS array
  const f16* sarr; f16* larr; int rbase;
  if (wid == 0)      { sarr = Ah_g; larr = &Ah[0][0]; rbase = m0; }
  else if (wid == 1) { sarr = Al_g; larr = &Al[0][0]; rbase = m0; }
  else if (wid == 2) { sarr = Bh_g; larr = &Bh[0][0]; rbase = n0; }
  else               { sarr = Bl_g; larr = &Bl[0][0]; rbase = n0; }
  const int lr = lane >> 2, lg = lane & 3;

  f32x4 acc1[4][4], acc2[4][4];
#pragma unroll
  for (int i = 0; i < 4; ++i)
#pragma unroll
    for (int j = 0; j < 4; ++j)
#pragma unroll
      for (int r = 0; r < 4; ++r) { acc1[i][j][r] = 0.0f; acc2[i][j][r] = 0.0f; }

  for (int kk = kb; kk < ke; kk += 32) {
    __syncthreads();   // previous compute done before overwrite
#pragma unroll
    for (int q = 0; q < 8; ++q) {
      const int r = q*16 + lr;
      const int sg = lg ^ ((r >> 1) & 3);
      gload_lds16(&sarr[(size_t)(rbase + r)*K + kk + sg*8], larr + q*512);
    }
    __syncthreads();   // compiler drains vmcnt before barrier -> data ready

    f16x8 bh[4], bl[4];
#pragma unroll
    for (int j = 0; j < 4; ++j) {
      const int rr = wc*64 + j*16 + frow;
      bh[j] = *(const f16x8*)&Bh[rr][swz];
      bl[j] = *(const f16x8*)&Bl[rr][swz];
    }
#pragma unroll
    for (int i = 0; i < 4; ++i) {
      const int rr = wr*64 + i*16 + frow;
      const f16x8 ah = *(const f16x8*)&Ah[rr][swz];
      const f16x8 al = *(const f16x8*)&Al[rr][swz];
#pragma unroll
      for (int j = 0; j < 4; ++j) {
        acc1[i][j] = __builtin_amdgcn_mfma_f32_16x16x32_f16(ah, bh[j], acc1[i][j], 0, 0, 0);
        acc2[i][j] = __builtin_amdgcn_mfma_f32_16x16x32_f16(ah, bl[j], acc2[i][j], 0, 0, 0);
        acc2[i][j] = __builtin_amdgcn_mfma_f32_16x16x32_f16(al, bh[j], acc2[i][j], 0, 0, 0);
      }
    }
  }

  const float s = 1.0f / 4096.0f;
#pragma unroll
  for (int i = 0; i < 4; ++i)
#pragma unroll
    for (int j = 0; j < 4; ++j) {
      const int col = n0 + wc*64 + j*16 + frow;
#pragma unroll
      for (int r = 0; r < 4; ++r) {
        const int row = m0 + wr*64 + i*16 + fkg*4 + r;
        atomicAdd(&Cout[(size_t)row*N + col], acc1[i][j][r] + acc2[i][j][r] * s);
      }
    }
}

// ---------------- heads (applies relu(h2f)) ----------------
__global__ __launch_bounds__(256) void heads_kernel(
    const float* __restrict__ h2f,
    const float* __restrict__ Wc, const float* __restrict__ bc,
    const float* __restrict__ Wo, const float* __restrict__ bo,
    const float* __restrict__ Wa, const float* __restrict__ ba,
    const float* __restrict__ bev_abs,
    float* __restrict__ obj_soft, float* __restrict__ boxes,
    float* __restrict__ orient, float* __restrict__ scores)
{
  const int r = blockIdx.x;
  const int tid = threadIdx.x;
  float acc[14];
#pragma unroll
  for (int j = 0; j < 14; ++j) acc[j] = 0.0f;
  for (int k = tid; k < HD; k += 256) {
    const float hv = fmaxf(h2f[(size_t)r*HD + k], 0.0f);
    acc[0]  += hv * Wc[k*2+0];
    acc[1]  += hv * Wc[k*2+1];
#pragma unroll
    for (int j = 0; j < 10; ++j) acc[2+j] += hv * Wo[k*10+j];
    acc[12] += hv * Wa[k*2+0];
    acc[13] += hv * Wa[k*2+1];
  }
  __shared__ float red[14][256];
#pragma unroll
  for (int j = 0; j < 14; ++j) red[j][tid] = acc[j];
  __syncthreads();
  for (int s = 128; s > 0; s >>= 1) {
    if (tid < s) {
#pragma unroll
      for (int j = 0; j < 14; ++j) red[j][tid] += red[j][tid + s];
    }
    __syncthreads();
  }
  if (tid == 0) {
    const float obj0 = red[0][0] + bc[0];
    const float obj1 = red[1][0] + bc[1];
    float off0 = red[2][0] + bo[0];
    float off1 = red[3][0] + bo[1];
    float off2 = red[4][0] + bo[2];
    float off3 = red[5][0] + bo[3];
    const float a0 = red[12][0] + ba[0];
    const float a1 = red[13][0] + ba[1];

    const float m  = fmaxf(obj0, obj1);
    const float e0 = expf(obj0 - m), e1 = expf(obj1 - m);
    const float se = e0 + e1;
    obj_soft[r*2+0] = e0 / se;
    obj_soft[r*2+1] = e1 / se;
    orient[r] = atan2f(a1, a0);

    const float pb0 = bev_abs[r*4+0] + 0.1f*off0;
    const float pb1 = bev_abs[r*4+1] + 0.1f*off1;
    const float pb2 = bev_abs[r*4+2] + 0.1f*off2;
    const float pb3 = bev_abs[r*4+3] + 0.1f*off3;
    boxes[r*4+0] = fminf(pb0, pb2);
    boxes[r*4+1] = fminf(pb1, pb3);
    boxes[r*4+2] = fmaxf(pb0, pb2);
    boxes[r*4+3] = fmaxf(pb1, pb3);
    scores[r] = obj1;
  }
}

// ---------------- NMS stage 1 ----------------
__global__ __launch_bounds__(128) void sort_kernel(
    const float* __restrict__ scores, const float* __restrict__ boxes,
    int* __restrict__ order, float4* __restrict__ sboxes, float* __restrict__ sarea)
{
  const int i = blockIdx.x * 128 + threadIdx.x;
  const float my = scores[i];
  int pos = 0;
  for (int j = 0; j < NBOX; ++j) {
    const float sj = scores[j];
    pos += (sj > my) || (sj == my && j < i);
  }
  const float b0 = boxes[i*4+0], b1 = boxes[i*4+1];
  const float b2 = boxes[i*4+2], b3 = boxes[i*4+3];
  order[pos]  = i;
  sboxes[pos] = make_float4(b0, b1, b2, b3);
  sarea[pos]  = fmaxf(b2 - b0, 0.0f) * fmaxf(b3 - b1, 0.0f);
}

// ---------------- NMS stage 2 ----------------
__device__ __forceinline__ int tri_base(int i) {
  const int b = i >> 6;
  return 64*(16*b - (b*(b-1))/2) + (i & 63)*(16 - b);
}

__global__ __launch_bounds__(256) void maskbuild_kernel(
    const float4* __restrict__ sboxes, const float* __restrict__ sarea,
    unsigned long long* __restrict__ Mtri)
{
  __shared__ float4 sb[NBOX];
  __shared__ float  sa[NBOX];
  const int tid = threadIdx.x;
  for (int t = tid; t < NBOX; t += 256) { sb[t] = sboxes[t]; sa[t] = sarea[t]; }
  __syncthreads();
  const int wv = tid >> 6, lane = tid & 63;
  for (int r = 0; r < 4; ++r) {
    const int i = blockIdx.x * 16 + wv * 4 + r;
    const float4 bi = sb[i];
    const float  ai = sa[i];
    const int b = i >> 6;
    const int base = tri_base(i);
    for (int w = b; w < 16; ++w) {
      const int j = w * 64 + lane;
      const float4 bj = sb[j];
      const float lt0 = fmaxf(bi.x, bj.x), lt1 = fmaxf(bi.y, bj.y);
      const float rb0 = fminf(bi.z, bj.z), rb1 = fminf(bi.w, bj.w);
      const float wq = fmaxf(rb0 - lt0, 0.0f), hq = fmaxf(rb1 - lt1, 0.0f);
      const float inter = wq * hq;
      const float iou = inter / (ai + sa[j] - inter + 1e-8f);
      const unsigned long long bits = __ballot((j > i) && (iou > NMS_THR_F));
      if (lane == 0) Mtri[base + (w - b)] = bits;
    }
  }
}

// ---------------- NMS stage 3 ----------------
__global__ __launch_bounds__(1024) void scan_out_kernel(
    const unsigned long long* __restrict__ Mtri_g, const int* __restrict__ order,
    const float4* __restrict__ sboxes, const float* __restrict__ obj_soft,
    const float* __restrict__ orient, float* __restrict__ out)
{
  __shared__ unsigned long long M[MTRI_WORDS];
  __shared__ unsigned long long keepw[16];
  const int tid = threadIdx.x;
  for (int t = tid; t < MTRI_WORDS; t += 1024) M[t] = Mtri_g[t];
  __syncthreads();

  if (tid < 64) {
    const int lane = tid;
    unsigned long long kw = (lane < 16) ? ~0ull : 0ull;
    for (int w = 0; w < 16; ++w) {
      unsigned long long rem = __shfl(kw, w);
      while (rem) {
        const int bpos = __builtin_ctzll(rem);
        const int i = w * 64 + bpos;
        const int base = tri_base(i);
        unsigned long long m = 0;
        if (lane >= w && lane < 16) m = M[base + (lane - w)];
        kw &= ~m;
        const unsigned long long updated = __shfl(kw, w);
        rem = (bpos == 63) ? 0ull : (updated & (~0ull << (bpos + 1)));
      }
    }
    if (lane < 16) keepw[lane] = kw;
  }
  __syncthreads();

  const int w = tid >> 6, bpos = tid & 63;
  int pre = 0, total = 0;
#pragma unroll
  for (int q = 0; q < 16; ++q) {
    const int pc = __popcll(keepw[q]);
    total += pc;
    if (q < w) pre += pc;
  }
  pre += __popcll(keepw[w] & ((bpos == 0) ? 0ull : (~0ull >> (64 - bpos))));
  const int keep_self = (int)((keepw[w] >> bpos) & 1ull);
  const int rank = keep_self ? pre : (total + tid - pre);

  if (rank < NMS_OUT) {
    const int ob = order[tid];
    const float4 bx = sboxes[tid];
    out[rank*7+0] = obj_soft[ob*2+0];
    out[rank*7+1] = obj_soft[ob*2+1];
    out[rank*7+2] = bx.x;
    out[rank*7+3] = bx.y;
    out[rank*7+4] = bx.z;
    out[rank*7+5] = bx.w;
    out[rank*7+6] = orient[ob];
  }
}

extern "C" void kernel_launch(void* const* d_in, const int* in_sizes, int n_in,
                              void* d_out, int out_size, void* d_ws, size_t ws_size,
                              hipStream_t stream) {
  (void)in_sizes; (void)n_in; (void)out_size; (void)ws_size;
  const float* img       = (const float*)d_in[0];
  const float* bev       = (const float*)d_in[1];
  const float* img_boxes = (const float*)d_in[2];
  const float* bev_boxes = (const float*)d_in[3];
  const float* bev_abs   = (const float*)d_in[4];
  const float* img_mask  = (const float*)d_in[5];
  const float* bev_mask  = (const float*)d_in[6];
  const float* W1 = (const float*)d_in[7];
  const float* b1 = (const float*)d_in[8];
  const float* W2 = (const float*)d_in[9];
  const float* b2 = (const float*)d_in[10];
  const float* Wc = (const float*)d_in[11];
  const float* bc = (const float*)d_in[12];
  const float* Wo = (const float*)d_in[13];
  const float* bo = (const float*)d_in[14];
  const float* Wa = (const float*)d_in[15];
  const float* ba = (const float*)d_in[16];
  float* out = (float*)d_out;

  char* ws = (char*)d_ws;
  f16* xh    = (f16*)ws;                                  ws += (size_t)NBOX*K1PAD*2;
  f16* xl    = (f16*)ws;                                  ws += (size_t)NBOX*K1PAD*2;
  float* h1f = (float*)ws;                                ws += (size_t)NBOX*HD*4;
  f16* h1h   = (f16*)ws;                                  ws += (size_t)NBOX*HD*2;
  f16* h1l   = (f16*)ws;                                  ws += (size_t)NBOX*HD*2;
  float* h2f = (float*)ws;                                ws += (size_t)NBOX*HD*4;
  f16* Wt1h  = (f16*)ws;                                  ws += (size_t)HD*K1PAD*2;
  f16* Wt1l  = (f16*)ws;                                  ws += (size_t)HD*K1PAD*2;
  f16* Wt2h  = (f16*)ws;                                  ws += (size_t)HD*HD*2;
  f16* Wt2l  = (f16*)ws;                                  ws += (size_t)HD*HD*2;
  float* obj_soft = (float*)ws;                           ws += NBOX*2*4;
  float* boxesf   = (float*)ws;                           ws += NBOX*4*4;
  float* orient   = (float*)ws;                           ws += NBOX*4;
  float* scores   = (float*)ws;                           ws += NBOX*4;
  int*   order    = (int*)ws;                             ws += NBOX*4;
  float4* sboxes  = (float4*)ws;                          ws += NBOX*16;
  float* sarea    = (float*)ws;                           ws += NBOX*4;
  unsigned long long* Mtri = (unsigned long long*)ws;

  prep_kernel<<<B_ROI + B_C1 + B_C2 + B_INIT, 256, 0, stream>>>(
      img, bev, img_boxes, bev_boxes, img_mask, bev_mask, xh, xl,
      W1, Wt1h, Wt1l, W2, Wt2h, Wt2l, b1, b2, (float4*)h1f, (float4*)h2f);
  // gemm1: h1f = b1 + x @ W1
  gemm_sk<<<512, 256, 0, stream>>>(xh, xl, Wt1h, Wt1l, h1f, NBOX, HD, K1PAD, K1PAD/4);
  // relu + split h1
  split_relu_kernel<<<NBOX*HD/4/256, 256, 0, stream>>>(h1f, h1h, h1l);
  // gemm2: h2f = b2 + relu(h1) @ W2
  gemm_sk<<<512, 256, 0, stream>>>(h1h, h1l, Wt2h, Wt2l, h2f, NBOX, HD, HD, HD/4);
  heads_kernel<<<NBOX, 256, 0, stream>>>(h2f, Wc, bc, Wo, bo, Wa, ba, bev_abs,
                                         obj_soft, boxesf, orient, scores);
  sort_kernel<<<8, 128, 0, stream>>>(scores, boxesf, order, sboxes, sarea);
  maskbuild_kernel<<<64, 256, 0, stream>>>(sboxes, sarea, Mtri);
  scan_out_kernel<<<1, 1024, 0, stream>>>(Mtri, order, sboxes, obj_soft, orient, out);
}

// Round 8
// 345.339 us; speedup vs baseline: 1.0872x; 1.0401x over previous
//
#include <hip/hip_runtime.h>
#include <math.h>

#define NBOX 1024
#define ROI_N 7
#define CH 32
#define FEAT (ROI_N*ROI_N*CH)   // 1568
#define K1PAD 1664              // FEAT padded to multiple of 128
#define HD 2048
#define NMS_THR_F 0.01f
#define NMS_OUT 100
#define MTRI_WORDS 8704

typedef _Float16 f16;
typedef f16 f16x4 __attribute__((ext_vector_type(4)));
typedef f16 f16x8 __attribute__((ext_vector_type(8)));
typedef float f32x4 __attribute__((ext_vector_type(4)));

__device__ __forceinline__ void split_f16(float v, f16& h, f16& l) {
  h = (f16)v;
  l = (f16)((v - (float)h) * 4096.0f);
}

__device__ __forceinline__ void gload_lds16(const void* g, void* l) {
  __builtin_amdgcn_global_load_lds(
      (const __attribute__((address_space(1))) unsigned int*)g,
      (__attribute__((address_space(3))) unsigned int*)l, 16, 0, 0);
}

// ============ prep: roi_fuse + convt(W1/W2) + bias-init + head-weight transpose ============
#define B_ROI 1024
#define B_C1  (64*26)    // (HD/32) x (K1PAD/64)
#define B_C2  (64*32)    // (HD/32) x (HD/64)
#define B_INIT 2048      // NBOX*HD/4/256
#define B_HT  112        // 14*HD/256

__device__ void roi_part(int b, int tid,
    const float* __restrict__ img, const float* __restrict__ bev,
    const float* __restrict__ img_boxes, const float* __restrict__ bev_boxes,
    float mi, float mb, f16* __restrict__ xh, f16* __restrict__ xl)
{
  const float denom = mi + mb;
  if (tid >= 196) {
    const int g = tid - 196;
    if (g < 12) {
      f16x8 z = {};
      *(f16x8*)&xh[(size_t)b*K1PAD + FEAT + g*8] = z;
      *(f16x8*)&xl[(size_t)b*K1PAD + FEAT + g*8] = z;
    }
    return;
  }
  const int cell = tid >> 2, cg = (tid & 3) * 8;
  const int ti = cell / ROI_N, tj = cell - ti*ROI_N;
  const float tt_i = (ti == 6) ? 1.0f : ti * (1.0f/6.0f);
  const float tt_j = (tj == 6) ? 1.0f : tj * (1.0f/6.0f);

  float vi[8], vb[8];
  {
    const int H = 360, W = 1200;
    const float iy0 = img_boxes[b*4+0], ix0 = img_boxes[b*4+1];
    const float iy1 = img_boxes[b*4+2], ix1 = img_boxes[b*4+3];
    const float ys = (iy0 + (iy1 - iy0) * tt_i) * (float)(H-1);
    const float xs = (ix0 + (ix1 - ix0) * tt_j) * (float)(W-1);
    int y0 = (int)floorf(ys); y0 = y0 < 0 ? 0 : (y0 > H-1 ? H-1 : y0);
    int x0 = (int)floorf(xs); x0 = x0 < 0 ? 0 : (x0 > W-1 ? W-1 : x0);
    const int y1 = (y0+1 > H-1) ? H-1 : y0+1;
    const int x1 = (x0+1 > W-1) ? W-1 : x0+1;
    const float wy = ys - (float)y0, wx = xs - (float)x0;
    const float w00 = (1.0f-wy)*(1.0f-wx), w01 = (1.0f-wy)*wx;
    const float w10 = wy*(1.0f-wx),        w11 = wy*wx;
    const float* p00 = &img[(y0*W + x0)*CH + cg];
    const float* p01 = &img[(y0*W + x1)*CH + cg];
    const float* p10 = &img[(y1*W + x0)*CH + cg];
    const float* p11 = &img[(y1*W + x1)*CH + cg];
#pragma unroll
    for (int q = 0; q < 2; ++q) {
      const float4 f00 = *(const float4*)(p00 + q*4);
      const float4 f01 = *(const float4*)(p01 + q*4);
      const float4 f10 = *(const float4*)(p10 + q*4);
      const float4 f11 = *(const float4*)(p11 + q*4);
      vi[q*4+0] = f00.x*w00 + f01.x*w01 + f10.x*w10 + f11.x*w11;
      vi[q*4+1] = f00.y*w00 + f01.y*w01 + f10.y*w10 + f11.y*w11;
      vi[q*4+2] = f00.z*w00 + f01.z*w01 + f10.z*w10 + f11.z*w11;
      vi[q*4+3] = f00.w*w00 + f01.w*w01 + f10.w*w10 + f11.w*w11;
    }
  }
  {
    const int H = 700, W = 800;
    const float by0 = bev_boxes[b*4+0], bx0 = bev_boxes[b*4+1];
    const float by1 = bev_boxes[b*4+2], bx1 = bev_boxes[b*4+3];
    const float ys = (by0 + (by1 - by0) * tt_i) * (float)(H-1);
    const float xs = (bx0 + (bx1 - bx0) * tt_j) * (float)(W-1);
    int y0 = (int)floorf(ys); y0 = y0 < 0 ? 0 : (y0 > H-1 ? H-1 : y0);
    int x0 = (int)floorf(xs); x0 = x0 < 0 ? 0 : (x0 > W-1 ? W-1 : x0);
    const int y1 = (y0+1 > H-1) ? H-1 : y0+1;
    const int x1 = (x0+1 > W-1) ? W-1 : x0+1;
    const float wy = ys - (float)y0, wx = xs - (float)x0;
    const float w00 = (1.0f-wy)*(1.0f-wx), w01 = (1.0f-wy)*wx;
    const float w10 = wy*(1.0f-wx),        w11 = wy*wx;
    const float* p00 = &bev[(y0*W + x0)*CH + cg];
    const float* p01 = &bev[(y0*W + x1)*CH + cg];
    const float* p10 = &bev[(y1*W + x0)*CH + cg];
    const float* p11 = &bev[(y1*W + x1)*CH + cg];
#pragma unroll
    for (int q = 0; q < 2; ++q) {
      const float4 f00 = *(const float4*)(p00 + q*4);
      const float4 f01 = *(const float4*)(p01 + q*4);
      const float4 f10 = *(const float4*)(p10 + q*4);
      const float4 f11 = *(const float4*)(p11 + q*4);
      vb[q*4+0] = f00.x*w00 + f01.x*w01 + f10.x*w10 + f11.x*w11;
      vb[q*4+1] = f00.y*w00 + f01.y*w01 + f10.y*w10 + f11.y*w11;
      vb[q*4+2] = f00.z*w00 + f01.z*w01 + f10.z*w10 + f11.z*w11;
      vb[q*4+3] = f00.w*w00 + f01.w*w01 + f10.w*w10 + f11.w*w11;
    }
  }
  f16x8 h8, l8;
#pragma unroll
  for (int q = 0; q < 8; ++q) {
    f16 h, l;
    split_f16((mi*vi[q] + mb*vb[q]) / denom, h, l);
    h8[q] = h; l8[q] = l;
  }
  const size_t o = (size_t)b*K1PAD + cell*32 + cg;
  *(f16x8*)&xh[o] = h8;
  *(f16x8*)&xl[o] = l8;
}

__global__ __launch_bounds__(256) void prep_kernel(
    const float* __restrict__ img, const float* __restrict__ bev,
    const float* __restrict__ img_boxes, const float* __restrict__ bev_boxes,
    const float* __restrict__ img_mask, const float* __restrict__ bev_mask,
    f16* __restrict__ xh, f16* __restrict__ xl,
    const float* __restrict__ W1, f16* __restrict__ Wt1h, f16* __restrict__ Wt1l,
    const float* __restrict__ W2, f16* __restrict__ Wt2h, f16* __restrict__ Wt2l,
    const float* __restrict__ b1, const float* __restrict__ b2,
    float4* __restrict__ h1f, float4* __restrict__ h2f,
    const float* __restrict__ Wc, const float* __restrict__ Wo,
    const float* __restrict__ Wa, float* __restrict__ Wcat)
{
  __shared__ float t[64][33];
  const int g = blockIdx.x;
  const int tid = threadIdx.x;

  if (g < B_ROI) {
    roi_part(g, tid, img, bev, img_boxes, bev_boxes, img_mask[0], bev_mask[0], xh, xl);
    return;
  }
  if (g >= B_ROI + B_C1 + B_C2 + B_INIT) {   // head-weight transpose
    const int idx = (g - (B_ROI + B_C1 + B_C2 + B_INIT))*256 + tid;  // 0..14*HD-1
    const int j = idx >> 11, k = idx & (HD-1);
    float v;
    if (j < 2)       v = Wc[k*2 + j];
    else if (j < 12) v = Wo[k*10 + (j-2)];
    else             v = Wa[k*2 + (j-12)];
    Wcat[idx] = v;
    return;
  }
  const float* W; f16 *Wh, *Wl; int K, Kpad, cb;
  if (g < B_ROI + B_C1) { cb = g - B_ROI;        W = W1; Wh = Wt1h; Wl = Wt1l; K = FEAT; Kpad = K1PAD; }
  else if (g < B_ROI + B_C1 + B_C2) { cb = g - B_ROI - B_C1; W = W2; Wh = Wt2h; Wl = Wt2l; K = HD; Kpad = HD; }
  else {
    const int ib = g - B_ROI - B_C1 - B_C2;
    const int idx = ib*256 + tid;
    const int c4 = idx & (HD/4 - 1);
    h1f[idx] = *(const float4*)&b1[c4*4];
    h2f[idx] = *(const float4*)&b2[c4*4];
    return;
  }
  const int nt = cb & 63, kt = cb >> 6;
  const int n0 = nt * 32, k0 = kt * 64;
#pragma unroll
  for (int p = 0; p < 8; ++p) {
    const int idx = tid + p*256;
    const int kk = idx >> 5, nn = idx & 31;
    const int k = k0 + kk;
    t[kk][nn] = (k < K) ? W[(size_t)k*HD + n0 + nn] : 0.0f;
  }
  __syncthreads();
  const int nn = tid >> 3;
  const int kg = (tid & 7) * 8;
  f16x8 h8, l8;
#pragma unroll
  for (int q = 0; q < 8; ++q) {
    f16 h, l;
    split_f16(t[kg + q][nn], h, l);
    h8[q] = h; l8[q] = l;
  }
  *(f16x8*)&Wh[(size_t)(n0+nn)*Kpad + k0 + kg] = h8;
  *(f16x8*)&Wl[(size_t)(n0+nn)*Kpad + k0 + kg] = l8;
}

// ---------------- relu + f16 hi/lo split of h1 ----------------
__global__ __launch_bounds__(256) void split_relu_kernel(
    const float* __restrict__ in, f16* __restrict__ oh, f16* __restrict__ ol)
{
  const int idx = blockIdx.x*256 + threadIdx.x;
  const float4 v = *(const float4*)&in[idx*4];
  f16x4 h4, l4;
  { f16 h,l; split_f16(fmaxf(v.x,0.0f),h,l); h4[0]=h; l4[0]=l; }
  { f16 h,l; split_f16(fmaxf(v.y,0.0f),h,l); h4[1]=h; l4[1]=l; }
  { f16 h,l; split_f16(fmaxf(v.z,0.0f),h,l); h4[2]=h; l4[2]=l; }
  { f16 h,l; split_f16(fmaxf(v.w,0.0f),h,l); h4[3]=h; l4[3]=l; }
  *(f16x4*)&oh[idx*4] = h4;
  *(f16x4*)&ol[idx*4] = l4;
}

// ---------------- MFMA GEMM: split-K=4 atomics, double-buffered global_load_lds ----------------
// Cout (pre-init with bias) += (Ah+Al/4096) @ (Bh+Bl/4096)^T, dropping lo*lo.
// Block 256 thr = 4 waves (2x2), tile 128x128, BK=32, 2-phase dbuf (T3 minimum recipe).
#define STAGE(BUF, KK)                                                        \
  do {                                                                        \
    _Pragma("unroll")                                                         \
    for (int q_ = 0; q_ < 8; ++q_) {                                          \
      const int r_ = q_*16 + lr;                                              \
      const int sg_ = lg ^ ((r_ >> 1) & 3);                                   \
      gload_lds16(&sarr[(size_t)(rbase + r_)*K + (KK) + sg_*8],               \
                  lbase + (BUF)*16384 + q_*512);                              \
    }                                                                         \
  } while (0)

__global__ __launch_bounds__(256, 2) void gemm_sk(
    const f16* __restrict__ Ah_g, const f16* __restrict__ Al_g,
    const f16* __restrict__ Bh_g, const f16* __restrict__ Bl_g,
    float* __restrict__ Cout, int M, int N, int K, int kchunk)
{
  __shared__ __align__(16) f16 lds[2][4][128*32];   // [buf][arr][row*32+col], 64 KB
  const int tid = threadIdx.x;

  const int g = blockIdx.x;
  const int xcd = g & 7, c = g >> 3;
  const int nb = xcd*2 + (c & 1);
  const int mb = (c >> 1) & 7;
  const int zb = c >> 4;
  const int m0 = mb * 128, n0 = nb * 128;
  const int kb = zb * kchunk, ke = kb + kchunk;

  const int wid = tid >> 6, lane = tid & 63;
  const int wr = wid >> 1, wc = wid & 1;
  const int frow = lane & 15, fkg = lane >> 4;
  const int swz = (fkg ^ ((frow >> 1) & 3)) * 8;

  // per-wave staging: wave -> one of the 4 arrays
  const f16* sarr; int rbase;
  if (wid == 0)      { sarr = Ah_g; rbase = m0; }
  else if (wid == 1) { sarr = Al_g; rbase = m0; }
  else if (wid == 2) { sarr = Bh_g; rbase = n0; }
  else               { sarr = Bl_g; rbase = n0; }
  f16* lbase = &lds[0][wid][0];
  const int lr = lane >> 2, lg = lane & 3;

  f32x4 acc1[4][4], acc2[4][4];
#pragma unroll
  for (int i = 0; i < 4; ++i)
#pragma unroll
    for (int j = 0; j < 4; ++j)
#pragma unroll
      for (int r = 0; r < 4; ++r) { acc1[i][j][r] = 0.0f; acc2[i][j][r] = 0.0f; }

  STAGE(0, kb);
  __syncthreads();                       // prologue loads landed
  int cur = 0;
  for (int kk = kb; kk < ke; kk += 32) {
    if (kk + 32 < ke) STAGE(cur ^ 1, kk + 32);   // prefetch next tile (overlaps MFMA below)

    const f16* bc_ = &lds[cur][0][0];
    f16x8 bh[4], bl[4];
#pragma unroll
    for (int j = 0; j < 4; ++j) {
      const int rr = wc*64 + j*16 + frow;
      bh[j] = *(const f16x8*)(bc_ + 8192  + rr*32 + swz);
      bl[j] = *(const f16x8*)(bc_ + 12288 + rr*32 + swz);
    }
#pragma unroll
    for (int i = 0; i < 4; ++i) {
      const int rr = wr*64 + i*16 + frow;
      const f16x8 ah = *(const f16x8*)(bc_ +        rr*32 + swz);
      const f16x8 al = *(const f16x8*)(bc_ + 4096 + rr*32 + swz);
#pragma unroll
      for (int j = 0; j < 4; ++j) {
        acc1[i][j] = __builtin_amdgcn_mfma_f32_16x16x32_f16(ah, bh[j], acc1[i][j], 0, 0, 0);
        acc2[i][j] = __builtin_amdgcn_mfma_f32_16x16x32_f16(ah, bl[j], acc2[i][j], 0, 0, 0);
        acc2[i][j] = __builtin_amdgcn_mfma_f32_16x16x32_f16(al, bh[j], acc2[i][j], 0, 0, 0);
      }
    }
    __syncthreads();                     // drains staged loads; frees cur for overwrite
    cur ^= 1;
  }

  const float s = 1.0f / 4096.0f;
#pragma unroll
  for (int i = 0; i < 4; ++i)
#pragma unroll
    for (int j = 0; j < 4; ++j) {
      const int col = n0 + wc*64 + j*16 + frow;
#pragma unroll
      for (int r = 0; r < 4; ++r) {
        const int row = m0 + wr*64 + i*16 + fkg*4 + r;
        atomicAdd(&Cout[(size_t)row*N + col], acc1[i][j][r] + acc2[i][j][r] * s);
      }
    }
}

// ---------------- heads: vectorized via transposed Wcat[14][HD] ----------------
__global__ __launch_bounds__(256) void heads_kernel(
    const float* __restrict__ h2f, const float* __restrict__ Wcat,
    const float* __restrict__ bc, const float* __restrict__ bo,
    const float* __restrict__ ba, const float* __restrict__ bev_abs,
    float* __restrict__ obj_soft, float* __restrict__ boxes,
    float* __restrict__ orient, float* __restrict__ scores)
{
  const int r = blockIdx.x;
  const int tid = threadIdx.x;
  const int k0 = tid * 8;
  float4 hv0 = *(const float4*)&h2f[(size_t)r*HD + k0];
  float4 hv1 = *(const float4*)&h2f[(size_t)r*HD + k0 + 4];
  hv0.x = fmaxf(hv0.x, 0.0f); hv0.y = fmaxf(hv0.y, 0.0f);
  hv0.z = fmaxf(hv0.z, 0.0f); hv0.w = fmaxf(hv0.w, 0.0f);
  hv1.x = fmaxf(hv1.x, 0.0f); hv1.y = fmaxf(hv1.y, 0.0f);
  hv1.z = fmaxf(hv1.z, 0.0f); hv1.w = fmaxf(hv1.w, 0.0f);

  float acc[14];
#pragma unroll
  for (int j = 0; j < 14; ++j) {
    const float4 w0 = *(const float4*)&Wcat[j*HD + k0];
    const float4 w1 = *(const float4*)&Wcat[j*HD + k0 + 4];
    acc[j] = hv0.x*w0.x + hv0.y*w0.y + hv0.z*w0.z + hv0.w*w0.w
           + hv1.x*w1.x + hv1.y*w1.y + hv1.z*w1.z + hv1.w*w1.w;
  }
  __shared__ float red[14][256];
#pragma unroll
  for (int j = 0; j < 14; ++j) red[j][tid] = acc[j];
  __syncthreads();
  for (int s = 128; s > 0; s >>= 1) {
    if (tid < s) {
#pragma unroll
      for (int j = 0; j < 14; ++j) red[j][tid] += red[j][tid + s];
    }
    __syncthreads();
  }
  if (tid == 0) {
    const float obj0 = red[0][0] + bc[0];
    const float obj1 = red[1][0] + bc[1];
    const float off0 = red[2][0] + bo[0];
    const float off1 = red[3][0] + bo[1];
    const float off2 = red[4][0] + bo[2];
    const float off3 = red[5][0] + bo[3];
    const float a0 = red[12][0] + ba[0];
    const float a1 = red[13][0] + ba[1];

    const float m  = fmaxf(obj0, obj1);
    const float e0 = expf(obj0 - m), e1 = expf(obj1 - m);
    const float se = e0 + e1;
    obj_soft[r*2+0] = e0 / se;
    obj_soft[r*2+1] = e1 / se;
    orient[r] = atan2f(a1, a0);

    const float pb0 = bev_abs[r*4+0] + 0.1f*off0;
    const float pb1 = bev_abs[r*4+1] + 0.1f*off1;
    const float pb2 = bev_abs[r*4+2] + 0.1f*off2;
    const float pb3 = bev_abs[r*4+3] + 0.1f*off3;
    boxes[r*4+0] = fminf(pb0, pb2);
    boxes[r*4+1] = fminf(pb1, pb3);
    boxes[r*4+2] = fmaxf(pb0, pb2);
    boxes[r*4+3] = fmaxf(pb1, pb3);
    scores[r] = obj1;
  }
}

// ---------------- NMS stage 1 (scores staged in LDS) ----------------
__global__ __launch_bounds__(128) void sort_kernel(
    const float* __restrict__ scores, const float* __restrict__ boxes,
    int* __restrict__ order, float4* __restrict__ sboxes, float* __restrict__ sarea)
{
  __shared__ float ss[NBOX];
  const int tid = threadIdx.x;
  for (int t = tid; t < NBOX; t += 128) ss[t] = scores[t];
  __syncthreads();
  const int i = blockIdx.x * 128 + tid;
  const float my = ss[i];
  int pos = 0;
  for (int j = 0; j < NBOX; ++j) {
    const float sj = ss[j];
    pos += (sj > my) || (sj == my && j < i);
  }
  const float b0 = boxes[i*4+0], b1 = boxes[i*4+1];
  const float b2 = boxes[i*4+2], b3 = boxes[i*4+3];
  order[pos]  = i;
  sboxes[pos] = make_float4(b0, b1, b2, b3);
  sarea[pos]  = fmaxf(b2 - b0, 0.0f) * fmaxf(b3 - b1, 0.0f);
}

// ---------------- NMS stage 2 ----------------
__device__ __forceinline__ int tri_base(int i) {
  const int b = i >> 6;
  return 64*(16*b - (b*(b-1))/2) + (i & 63)*(16 - b);
}

__global__ __launch_bounds__(256) void maskbuild_kernel(
    const float4* __restrict__ sboxes, const float* __restrict__ sarea,
    unsigned long long* __restrict__ Mtri)
{
  __shared__ float4 sb[NBOX];
  __shared__ float  sa[NBOX];
  const int tid = threadIdx.x;
  for (int t = tid; t < NBOX; t += 256) { sb[t] = sboxes[t]; sa[t] = sarea[t]; }
  __syncthreads();
  const int wv = tid >> 6, lane = tid & 63;
  for (int r = 0; r < 4; ++r) {
    const int i = blockIdx.x * 16 + wv * 4 + r;
    const float4 bi = sb[i];
    const float  ai = sa[i];
    const int b = i >> 6;
    const int base = tri_base(i);
    for (int w = b; w < 16; ++w) {
      const int j = w * 64 + lane;
      const float4 bj = sb[j];
      const float lt0 = fmaxf(bi.x, bj.x), lt1 = fmaxf(bi.y, bj.y);
      const float rb0 = fminf(bi.z, bj.z), rb1 = fminf(bi.w, bj.w);
      const float wq = fmaxf(rb0 - lt0, 0.0f), hq = fmaxf(rb1 - lt1, 0.0f);
      const float inter = wq * hq;
      const float iou = inter / (ai + sa[j] - inter + 1e-8f);
      const unsigned long long bits = __ballot((j > i) && (iou > NMS_THR_F));
      if (lane == 0) Mtri[base + (w - b)] = bits;
    }
  }
}

// ---------------- NMS stage 3 ----------------
__global__ __launch_bounds__(1024) void scan_out_kernel(
    const unsigned long long* __restrict__ Mtri_g, const int* __restrict__ order,
    const float4* __restrict__ sboxes, const float* __restrict__ obj_soft,
    const float* __restrict__ orient, float* __restrict__ out)
{
  __shared__ unsigned long long M[MTRI_WORDS];
  __shared__ unsigned long long keepw[16];
  const int tid = threadIdx.x;
  for (int t = tid; t < MTRI_WORDS; t += 1024) M[t] = Mtri_g[t];
  __syncthreads();

  if (tid < 64) {
    const int lane = tid;
    unsigned long long kw = (lane < 16) ? ~0ull : 0ull;
    for (int w = 0; w < 16; ++w) {
      unsigned long long rem = __shfl(kw, w);
      while (rem) {
        const int bpos = __builtin_ctzll(rem);
        const int i = w * 64 + bpos;
        const int base = tri_base(i);
        unsigned long long m = 0;
        if (lane >= w && lane < 16) m = M[base + (lane - w)];
        kw &= ~m;
        const unsigned long long updated = __shfl(kw, w);
        rem = (bpos == 63) ? 0ull : (updated & (~0ull << (bpos + 1)));
      }
    }
    if (lane < 16) keepw[lane] = kw;
  }
  __syncthreads();

  const int w = tid >> 6, bpos = tid & 63;
  int pre = 0, total = 0;
#pragma unroll
  for (int q = 0; q < 16; ++q) {
    const int pc = __popcll(keepw[q]);
    total += pc;
    if (q < w) pre += pc;
  }
  pre += __popcll(keepw[w] & ((bpos == 0) ? 0ull : (~0ull >> (64 - bpos))));
  const int keep_self = (int)((keepw[w] >> bpos) & 1ull);
  const int rank = keep_self ? pre : (total + tid - pre);

  if (rank < NMS_OUT) {
    const int ob = order[tid];
    const float4 bx = sboxes[tid];
    out[rank*7+0] = obj_soft[ob*2+0];
    out[rank*7+1] = obj_soft[ob*2+1];
    out[rank*7+2] = bx.x;
    out[rank*7+3] = bx.y;
    out[rank*7+4] = bx.z;
    out[rank*7+5] = bx.w;
    out[rank*7+6] = orient[ob];
  }
}

extern "C" void kernel_launch(void* const* d_in, const int* in_sizes, int n_in,
                              void* d_out, int out_size, void* d_ws, size_t ws_size,
                              hipStream_t stream) {
  (void)in_sizes; (void)n_in; (void)out_size; (void)ws_size;
  const float* img       = (const float*)d_in[0];
  const float* bev       = (const float*)d_in[1];
  const float* img_boxes = (const float*)d_in[2];
  const float* bev_boxes = (const float*)d_in[3];
  const float* bev_abs   = (const float*)d_in[4];
  const float* img_mask  = (const float*)d_in[5];
  const float* bev_mask  = (const float*)d_in[6];
  const float* W1 = (const float*)d_in[7];
  const float* b1 = (const float*)d_in[8];
  const float* W2 = (const float*)d_in[9];
  const float* b2 = (const float*)d_in[10];
  const float* Wc = (const float*)d_in[11];
  const float* bc = (const float*)d_in[12];
  const float* Wo = (const float*)d_in[13];
  const float* bo = (const float*)d_in[14];
  const float* Wa = (const float*)d_in[15];
  const float* ba = (const float*)d_in[16];
  float* out = (float*)d_out;

  char* ws = (char*)d_ws;
  f16* xh    = (f16*)ws;                                  ws += (size_t)NBOX*K1PAD*2;
  f16* xl    = (f16*)ws;                                  ws += (size_t)NBOX*K1PAD*2;
  float* h1f = (float*)ws;                                ws += (size_t)NBOX*HD*4;
  f16* h1h   = (f16*)ws;                                  ws += (size_t)NBOX*HD*2;
  f16* h1l   = (f16*)ws;                                  ws += (size_t)NBOX*HD*2;
  float* h2f = (float*)ws;                                ws += (size_t)NBOX*HD*4;
  f16* Wt1h  = (f16*)ws;                                  ws += (size_t)HD*K1PAD*2;
  f16* Wt1l  = (f16*)ws;                                  ws += (size_t)HD*K1PAD*2;
  f16* Wt2h  = (f16*)ws;                                  ws += (size_t)HD*HD*2;
  f16* Wt2l  = (f16*)ws;                                  ws += (size_t)HD*HD*2;
  float* Wcat = (float*)ws;                               ws += 14*HD*4;
  float* obj_soft = (float*)ws;                           ws += NBOX*2*4;
  float* boxesf   = (float*)ws;                           ws += NBOX*4*4;
  float* orient   = (float*)ws;                           ws += NBOX*4;
  float* scores   = (float*)ws;                           ws += NBOX*4;
  int*   order    = (int*)ws;                             ws += NBOX*4;
  float4* sboxes  = (float4*)ws;                          ws += NBOX*16;
  float* sarea    = (float*)ws;                           ws += NBOX*4;
  unsigned long long* Mtri = (unsigned long long*)ws;

  prep_kernel<<<B_ROI + B_C1 + B_C2 + B_INIT + B_HT, 256, 0, stream>>>(
      img, bev, img_boxes, bev_boxes, img_mask, bev_mask, xh, xl,
      W1, Wt1h, Wt1l, W2, Wt2h, Wt2l, b1, b2, (float4*)h1f, (float4*)h2f,
      Wc, Wo, Wa, Wcat);
  gemm_sk<<<512, 256, 0, stream>>>(xh, xl, Wt1h, Wt1l, h1f, NBOX, HD, K1PAD, K1PAD/4);
  split_relu_kernel<<<NBOX*HD/4/256, 256, 0, stream>>>(h1f, h1h, h1l);
  gemm_sk<<<512, 256, 0, stream>>>(h1h, h1l, Wt2h, Wt2l, h2f, NBOX, HD, HD, HD/4);
  heads_kernel<<<NBOX, 256, 0, stream>>>(h2f, Wcat, bc, bo, ba, bev_abs,
                                         obj_soft, boxesf, orient, scores);
  sort_kernel<<<8, 128, 0, stream>>>(scores, boxesf, order, sboxes, sarea);
  maskbuild_kernel<<<64, 256, 0, stream>>>(sboxes, sarea, Mtri);
  scan_out_kernel<<<1, 1024, 0, stream>>>(Mtri, order, sboxes, obj_soft, orient, out);
}